// Round 12
// baseline (292.800 us; speedup 1.0000x reference)
//
#include <hip/hip_runtime.h>
#include <cstdint>
#include <cstddef>

#define NN 20000
#define NE 320000

typedef short short8 __attribute__((ext_vector_type(8)));
typedef float f32x4 __attribute__((ext_vector_type(4)));
typedef unsigned short u16;

__device__ __forceinline__ float b2f(u16 u) {
  union { unsigned int i; float f; } z; z.i = ((unsigned int)u) << 16; return z.f;
}
__device__ __forceinline__ u16 f2b(float f) {
  union { float f; unsigned int i; } z; z.f = f;
  unsigned int r = z.i + 0x7fffu + ((z.i >> 16) & 1u);
  return (u16)(r >> 16);
}
// fast ELU: v_exp_f32-based, not libm expm1f
__device__ __forceinline__ float eluf(float v) {
  return v > 0.0f ? v : __expf(v) - 1.0f;
}

// ------- fused prep: features f2b (column-SLICED out) + 7 weight transposes
//         + edge histogram. virtual tid space:
//         [0,1280000): f2b 4 elems ; [1280000,1600000): hist ; rest: weights.
// (R5/R9-proven version; R7/R8 restructure caused corruption — kept dead.)
__global__ __launch_bounds__(256) void k_prep(
    const float* __restrict__ features, u16* __restrict__ xbf_sliced,
    const int* __restrict__ edst, int* __restrict__ counts,
    const float* __restrict__ wr, const float* __restrict__ w1a,
    const float* __restrict__ w1b, const float* __restrict__ w2a,
    const float* __restrict__ w2b, const float* __restrict__ w3a,
    const float* __restrict__ w3b,
    u16* __restrict__ wrt, u16* __restrict__ w1at, u16* __restrict__ w1bt,
    u16* __restrict__ w2at, u16* __restrict__ w2bt, u16* __restrict__ w3at,
    u16* __restrict__ w3bt) {
  int tid = blockIdx.x * 256 + threadIdx.x;
  if (tid < 1280000) {
    int node = tid >> 6;
    int c4 = (tid & 63) * 4;           // col = c4..c4+3 (within one 64-slice)
    float4 v = *reinterpret_cast<const float4*>(features + (size_t)node * 256 + c4);
    ushort4 o;
    o.x = f2b(v.x); o.y = f2b(v.y); o.z = f2b(v.z); o.w = f2b(v.w);
    int slice = c4 >> 6, within = c4 & 63;
    *reinterpret_cast<ushort4*>(xbf_sliced + (size_t)slice * NN * 64 +
                                (size_t)node * 64 + within) = o;
    return;
  }
  if (tid < 1600000) {
    atomicAdd(&counts[edst[tid - 1280000]], 1);
    return;
  }
  int r = tid - 1600000;
  const float* Ws[7] = {wr, w1a, w1b, w2a, w2b, w3a, w3b};
  u16* Wts[7] = {wrt, w1at, w1bt, w2at, w2bt, w3at, w3bt};
  const int Kd[7] = {256, 256, 640, 640, 320, 320, 256};
  const int Nd[7] = {256, 640, 640, 320, 320, 256, 256};
  const int cnt[7] = {65536, 163840, 409600, 204800, 102400, 81920, 65536};
#pragma unroll
  for (int j = 0; j < 7; ++j) {
    if (r < cnt[j]) {
      int n = r / Kd[j], k = r - n * Kd[j];
      Wts[j][r] = f2b(Ws[j][(size_t)k * Nd[j] + n]);
      return;
    }
    r -= cnt[j];
  }
}

// x4-vectorized single-block scan; writes exclusive prefix to rs AND cur.
// ALSO builds the degree histogram (per-wave private LDS hists to avoid
// atomic serialization) and its 256-bin exclusive scan -> dcur, used by
// k_scatter to counting-sort nodes by degree (agg load balance).
__global__ __launch_bounds__(1024) void k_scan(const int* __restrict__ counts,
                                               int* __restrict__ rs,
                                               int* __restrict__ cur,
                                               int* __restrict__ dcur) {
  __shared__ int wsum[16];
  __shared__ int carry_s;
  __shared__ int wh[16][256];  // per-wave degree histograms
  int t = threadIdx.x;
  int l = t & 63, w = t >> 6;
  if (t == 0) carry_s = 0;
  for (int i = t; i < 16 * 256; i += 1024) ((int*)wh)[i] = 0;
  __syncthreads();
  for (int base = 0; base < NN; base += 4096) {
    int idx = base + t * 4;
    int4 v = {0, 0, 0, 0};
    if (idx < NN) {
      v = *reinterpret_cast<const int4*>(counts + idx);
      atomicAdd(&wh[w][v.x < 255 ? v.x : 255], 1);
      atomicAdd(&wh[w][v.y < 255 ? v.y : 255], 1);
      atomicAdd(&wh[w][v.z < 255 ? v.z : 255], 1);
      atomicAdd(&wh[w][v.w < 255 ? v.w : 255], 1);
    }
    int p0 = v.x, p1 = p0 + v.y, p2 = p1 + v.z, p3 = p2 + v.w;
    int incl = p3;
#pragma unroll
    for (int off = 1; off < 64; off <<= 1) {
      int u = __shfl_up(incl, off, 64);
      if (l >= off) incl += u;
    }
    if (l == 63) wsum[w] = incl;
    __syncthreads();  // (A) wsum ready
    int carry = carry_s;
    int wpre = 0;
    for (int k2 = 0; k2 < w; ++k2) wpre += wsum[k2];
    int tot = 0;
    if (t == 0)
      for (int k2 = 0; k2 < 16; ++k2) tot += wsum[k2];
    int ex = carry + wpre + incl - p3;
    if (idx < NN) {
      int4 o;
      o.x = ex; o.y = ex + p0; o.z = ex + p1; o.w = ex + p2;
      *reinterpret_cast<int4*>(rs + idx) = o;
      *reinterpret_cast<int4*>(cur + idx) = o;
    }
    __syncthreads();  // (B) all reads of wsum/carry_s done
    if (t == 0) carry_s = carry + tot;
    __syncthreads();  // (C) carry_s updated
  }
  if (t == 0) rs[NN] = carry_s;
  // ---- degree-histogram exclusive scan -> dcur (256 bins, 4 waves) ----
  __syncthreads();
  int dv = 0, incl = 0;
  if (t < 256) {
    int s = 0;
#pragma unroll
    for (int k2 = 0; k2 < 16; ++k2) s += wh[k2][t];
    dv = s;
    incl = s;
#pragma unroll
    for (int off = 1; off < 64; off <<= 1) {
      int u = __shfl_up(incl, off, 64);
      if (l >= off) incl += u;
    }
    if (l == 63) wsum[w] = incl;  // w in 0..3 here
  }
  __syncthreads();
  if (t < 256) {
    int basew = 0;
    for (int k2 = 0; k2 < w; ++k2) basew += wsum[k2];
    dcur[t] = basew + incl - dv;
  }
}

// edge scatter (CSR) + node counting-sort-by-degree scatter (perm) in one
// thread space: [0,NE) edges, [NE,NE+NN) nodes.
__global__ __launch_bounds__(256) void k_scatter(const int* __restrict__ src,
                                                 const int* __restrict__ dst,
                                                 int* __restrict__ cursor,
                                                 int* __restrict__ csr_src,
                                                 const int* __restrict__ counts,
                                                 int* __restrict__ dcur,
                                                 int* __restrict__ perm) {
  int i = blockIdx.x * 256 + threadIdx.x;
  if (i < NE) {
    int d = dst[i];
    int p = atomicAdd(&cursor[d], 1);
    csr_src[p] = src[i];
  } else if (i < NE + NN) {
    int nd = i - NE;
    int deg = counts[nd]; if (deg > 255) deg = 255;
    int p = atomicAdd(&dcur[deg], 1);
    perm[p] = nd;
  }
}

// ---- aggregation, COLUMN-SLICED gather source, DEGREE-SORTED node order ----
// xs layout: [4][NN][SW] bf16 (SW = D/4). Block's slice = (blockIdx&7)&3 so
// each XCD gathers from ONE L2-resident slice. Halves take even/odd positions
// of the degree-sorted perm -> equal degree distribution per half AND
// near-uniform degree within a block (block time ~ mean, not max).
template <int D, int ACT>
__global__ __launch_bounds__(256) void k_agg(const u16* __restrict__ xs,
                                             const int* __restrict__ rs,
                                             const int* __restrict__ cs,
                                             const int* __restrict__ perm,
                                             const float* __restrict__ bias,
                                             u16* __restrict__ h) {
  constexpr int SW = D / 4;       // slice width (64 or 80 cols)
  constexpr int NCs = SW / 8;     // 16B chunks per slice-row (8 or 10)
  constexpr int NPB = 256 / NCs;  // nodes per block (32 or 25)
  int b = blockIdx.x;
  int cls = b & 7;
  int slice = cls & 3;
  int half = cls >> 2;
  int t = threadIdx.x;
  int nl = t / NCs, ch = t - nl * NCs;
  if (nl >= NPB) return;  // only when 256 % NCs != 0
  int idx2 = (b >> 3) * NPB + nl;
  if (idx2 >= 10000) return;
  int node = perm[idx2 * 2 + half];
  const u16* xp = xs + (size_t)slice * NN * SW + (size_t)ch * 8;
  float acc[8];
  {
    short8 v = *reinterpret_cast<const short8*>(xp + (size_t)node * SW);
#pragma unroll
    for (int q = 0; q < 8; ++q) acc[q] = b2f((u16)v[q]);
  }
  int e0 = rs[node], e1 = rs[node + 1];
  int e = e0;
  // 16-wide unroll: 16 independent gathers in flight (latency-bound loop)
  for (; e + 16 <= e1; e += 16) {
    int s[16];
#pragma unroll
    for (int u = 0; u < 16; ++u) s[u] = cs[e + u];
    short8 v[16];
#pragma unroll
    for (int u = 0; u < 16; ++u)
      v[u] = *reinterpret_cast<const short8*>(xp + (size_t)s[u] * SW);
#pragma unroll
    for (int q = 0; q < 8; ++q) {
      float a0 = (b2f((u16)v[0][q]) + b2f((u16)v[1][q])) +
                 (b2f((u16)v[2][q]) + b2f((u16)v[3][q]));
      float a1 = (b2f((u16)v[4][q]) + b2f((u16)v[5][q])) +
                 (b2f((u16)v[6][q]) + b2f((u16)v[7][q]));
      float a2 = (b2f((u16)v[8][q]) + b2f((u16)v[9][q])) +
                 (b2f((u16)v[10][q]) + b2f((u16)v[11][q]));
      float a3 = (b2f((u16)v[12][q]) + b2f((u16)v[13][q])) +
                 (b2f((u16)v[14][q]) + b2f((u16)v[15][q]));
      acc[q] += (a0 + a1) + (a2 + a3);
    }
  }
  for (; e + 8 <= e1; e += 8) {
    int s[8];
#pragma unroll
    for (int u = 0; u < 8; ++u) s[u] = cs[e + u];
    short8 v[8];
#pragma unroll
    for (int u = 0; u < 8; ++u)
      v[u] = *reinterpret_cast<const short8*>(xp + (size_t)s[u] * SW);
#pragma unroll
    for (int q = 0; q < 8; ++q) {
      float a0 = b2f((u16)v[0][q]) + b2f((u16)v[1][q]);
      float a1 = b2f((u16)v[2][q]) + b2f((u16)v[3][q]);
      float a2 = b2f((u16)v[4][q]) + b2f((u16)v[5][q]);
      float a3 = b2f((u16)v[6][q]) + b2f((u16)v[7][q]);
      acc[q] += (a0 + a1) + (a2 + a3);
    }
  }
  for (; e + 4 <= e1; e += 4) {
    int s0 = cs[e], s1 = cs[e + 1], s2 = cs[e + 2], s3 = cs[e + 3];
    short8 v0 = *reinterpret_cast<const short8*>(xp + (size_t)s0 * SW);
    short8 v1 = *reinterpret_cast<const short8*>(xp + (size_t)s1 * SW);
    short8 v2 = *reinterpret_cast<const short8*>(xp + (size_t)s2 * SW);
    short8 v3 = *reinterpret_cast<const short8*>(xp + (size_t)s3 * SW);
#pragma unroll
    for (int q = 0; q < 8; ++q)
      acc[q] += (b2f((u16)v0[q]) + b2f((u16)v1[q])) + (b2f((u16)v2[q]) + b2f((u16)v3[q]));
  }
  for (; e < e1; ++e) {
    int s = cs[e];
    short8 v = *reinterpret_cast<const short8*>(xp + (size_t)s * SW);
#pragma unroll
    for (int q = 0; q < 8; ++q) acc[q] += b2f((u16)v[q]);
  }
  int col0 = slice * SW + ch * 8;
  if (ACT == 1) {
    float4 b0 = *reinterpret_cast<const float4*>(bias + col0);
    float4 b1 = *reinterpret_cast<const float4*>(bias + col0 + 4);
    acc[0] = eluf(acc[0] + b0.x); acc[1] = eluf(acc[1] + b0.y);
    acc[2] = eluf(acc[2] + b0.z); acc[3] = eluf(acc[3] + b0.w);
    acc[4] = eluf(acc[4] + b1.x); acc[5] = eluf(acc[5] + b1.y);
    acc[6] = eluf(acc[6] + b1.z); acc[7] = eluf(acc[7] + b1.w);
  }
  short8 o;
#pragma unroll
  for (int q = 0; q < 8; ++q) o[q] = (short)f2b(acc[q]);
  *reinterpret_cast<short8*>(h + (size_t)node * D + col0) = o;
}

// ---------------- GEMM: C = act(A[M][K] @ B[K][N] + bias) ----------------
// A bf16 [M][K] (or column-sliced [4][M][64] when INS), Bt bf16 [N][K].
// BMx128 tile, BK=32, SLOTS-deep prefetch ring with counted vmcnt + raw
// s_barrier, issue-order fences, setprio around MFMA, 4 waves, 16x16x32 bf16
// MFMA, swizzled LDS, XCD-chunked grid.
// SLOTS=2 -> 24-32KB (5-6 blk/CU); SLOTS=3 -> deeper pipeline.
template <int BM, int K, int N, int ACT, bool OUTF32, bool INS, int OSW, int SLOTS>
__global__ __launch_bounds__(256) void k_gemm(const u16* __restrict__ A,
                                              const u16* __restrict__ Bt,
                                              const float* __restrict__ bias,
                                              void* __restrict__ outp, int M) {
  constexpr int NBY = (N + 127) / 128;
  constexpr int NK = K / 32;
  constexpr int ABUF = BM * 32;       // u16 per A LDS buffer
  constexpr int BUFSZ = ABUF + 4096;  // A + B per ring slot
  constexpr int MI = BM / 32;         // acc i-extent per wave (2 or 4)
  constexpr int LPT = BM / 64 + 2;    // global_load_lds per thread per stage
  __shared__ __align__(16) u16 smem[SLOTS * BUFSZ];
  int t = threadIdx.x;
  int l = t & 63, w = t >> 6;
  int lm = l & 15, lk = l >> 4;

  // bijective XCD-chunked swizzle (m204)
  int nb = gridDim.x;
  int q8 = nb >> 3, r8 = nb & 7;
  int orig = blockIdx.x;
  int xcd = orig & 7, idx = orig >> 3;
  int wg = (xcd < r8 ? xcd * (q8 + 1) : r8 * (q8 + 1) + (xcd - r8) * q8) + idx;
  int m0 = (wg / NBY) * BM;
  int n0 = (wg % NBY) * 128;
  int wm = (w >> 1) * (BM / 2), wn = (w & 1) * 64;

  f32x4 acc[MI][4];
#pragma unroll
  for (int i = 0; i < MI; ++i)
#pragma unroll
    for (int j = 0; j < 4; ++j)
#pragma unroll
      for (int qq = 0; qq < 4; ++qq) acc[i][j][qq] = 0.0f;

  auto stage = [&](int buf, int kt) {
    int k0 = kt * 32;
    u16* As = smem + buf * BUFSZ;
    u16* Bs = As + ABUF;
#pragma unroll
    for (int it = 0; it < BM / 64; ++it) {  // A
      int c = it * 256 + t;
      int row = c >> 2;
      int kc = (c & 3) ^ ((c >> 3) & 3);
      int ra = m0 + row; ra = ra < M ? ra : M - 1;
      const u16* ga;
      if (INS)
        ga = A + (size_t)(k0 >> 6) * NN * 64 + (size_t)ra * 64 + (k0 & 63) + kc * 8;
      else
        ga = A + (size_t)ra * K + k0 + kc * 8;
      __builtin_amdgcn_global_load_lds(
          (const __attribute__((address_space(1))) void*)ga,
          (__attribute__((address_space(3))) void*)(As + c * 8), 16, 0, 0);
    }
#pragma unroll
    for (int it = 0; it < 2; ++it) {        // B: 128*32 u16
      int c = it * 256 + t;
      int row = c >> 2;
      int kc = (c & 3) ^ ((c >> 3) & 3);
      int rb = n0 + row; rb = rb < N ? rb : N - 1;
      const u16* gb = Bt + (size_t)rb * K + k0 + kc * 8;
      __builtin_amdgcn_global_load_lds(
          (const __attribute__((address_space(1))) void*)gb,
          (__attribute__((address_space(3))) void*)(Bs + c * 8), 16, 0, 0);
    }
  };

  int kidx = (lk ^ ((lm >> 1) & 3)) * 8;

#pragma unroll
  for (int s = 0; s < SLOTS; ++s) {
    stage(s, s);
    asm volatile("" ::: "memory");
  }
  int buf = 0;
  for (int kt = 0; kt < NK; ++kt) {
    int rem = NK - 1 - kt;
    if (SLOTS == 3) {
      if (rem >= 2)
        asm volatile("s_waitcnt vmcnt(%0)" ::"n"(2 * LPT) : "memory");
      else if (rem == 1)
        asm volatile("s_waitcnt vmcnt(%0)" ::"n"(LPT) : "memory");
      else
        asm volatile("s_waitcnt vmcnt(0)" ::: "memory");
    } else {
      if (rem >= 1)
        asm volatile("s_waitcnt vmcnt(%0)" ::"n"(LPT) : "memory");
      else
        asm volatile("s_waitcnt vmcnt(0)" ::: "memory");
    }
    __builtin_amdgcn_s_barrier();
    asm volatile("" ::: "memory");
    const u16* As = smem + buf * BUFSZ;
    const u16* Bs = As + ABUF;
    short8 af[MI], bf[4];
#pragma unroll
    for (int i = 0; i < MI; ++i)
      af[i] = *reinterpret_cast<const short8*>(As + (wm + i * 16 + lm) * 32 + kidx);
#pragma unroll
    for (int j = 0; j < 4; ++j)
      bf[j] = *reinterpret_cast<const short8*>(Bs + (wn + j * 16 + lm) * 32 + kidx);
    __builtin_amdgcn_s_setprio(1);
#pragma unroll
    for (int i = 0; i < MI; ++i)
#pragma unroll
      for (int j = 0; j < 4; ++j)
        acc[i][j] = __builtin_amdgcn_mfma_f32_16x16x32_bf16(af[i], bf[j], acc[i][j], 0, 0, 0);
    __builtin_amdgcn_s_setprio(0);
    asm volatile("s_waitcnt lgkmcnt(0)" ::: "memory");
    __builtin_amdgcn_s_barrier();
    asm volatile("" ::: "memory");
    if (kt + SLOTS < NK) stage(buf, kt + SLOTS);
    buf = (buf == SLOTS - 1) ? 0 : buf + 1;
  }

  // epilogue. C/D frag layout: row = i*16 + lk*4 + qq, col = j*16 + lm.
  if (!OUTF32) {
    u16* ep = smem + w * (BM / 2) * 64;
#pragma unroll
    for (int j = 0; j < 4; ++j) {
      int col = n0 + wn + j * 16 + lm;
      float bv = (ACT > 0) ? bias[col < N ? col : N - 1] : 0.0f;
#pragma unroll
      for (int i = 0; i < MI; ++i)
#pragma unroll
        for (int qq = 0; qq < 4; ++qq) {
          float v = acc[i][j][qq];
          if (ACT > 0) { v += bv; v = eluf(v); }
          if (ACT == 2) v = eluf(v);
          ep[(i * 16 + lk * 4 + qq) * 64 + j * 16 + lm] = f2b(v);
        }
    }
    __syncthreads();
    u16* op = (u16*)outp;
#pragma unroll
    for (int u = 0; u < BM / 16; ++u) {
      int rrow = m0 + wm + u * 8 + (l >> 3);
      int col = n0 + wn + (l & 7) * 8;
      if (rrow < M && col < N) {
        short8 val = *reinterpret_cast<const short8*>(ep + u * 512 + l * 8);
        if (OSW) {
          int slice = col / OSW, within = col - slice * OSW;
          *reinterpret_cast<short8*>(op + (size_t)slice * NN * OSW +
                                     (size_t)rrow * OSW + within) = val;
        } else {
          *reinterpret_cast<short8*>(op + (size_t)rrow * N + col) = val;
        }
      }
    }
  } else {
    float* op = (float*)outp;
#pragma unroll
    for (int j = 0; j < 4; ++j) {
      int col = n0 + wn + j * 16 + lm;
      if (col >= N) continue;
      float bv = (ACT > 0) ? bias[col] : 0.0f;
#pragma unroll
      for (int i = 0; i < MI; ++i) {
        int rb = m0 + wm + i * 16 + lk * 4;
#pragma unroll
        for (int qq = 0; qq < 4; ++qq) {
          int rr = rb + qq;
          if (rr >= M) continue;
          float v = acc[i][j][qq];
          if (ACT > 0) { v += bv; v = eluf(v); }
          if (ACT == 2) v = eluf(v);
          op[(size_t)rr * N + col] = v;
        }
      }
    }
  }
}

// ---- DUAL GEMM: two independent K=256,N=256,BM=64,ACT=1,fp32-out GEMMs in
// one launch (x tiles [0,NT0), res tiles [NT0,2*NT0); res reads sliced X).
__global__ __launch_bounds__(256) void k_gemmd(
    const u16* __restrict__ A0, const u16* __restrict__ Bt0,
    const float* __restrict__ bias0, float* __restrict__ out0,
    const u16* __restrict__ A1, const u16* __restrict__ Bt1,
    const float* __restrict__ bias1, float* __restrict__ out1) {
  constexpr int K = 256, N = 256, BM = 64;
  constexpr int NBY = 2, NK = 8, NT0 = 626;
  constexpr int ABUF = BM * 32, BUFSZ = ABUF + 4096, MI = 2, LPT = 3;
  constexpr int SLOTS = 2;  // 24KB -> 6 blk/CU; grid 1252 <= 1536 single round
  __shared__ __align__(16) u16 smem[SLOTS * BUFSZ];
  int t = threadIdx.x;
  int l = t & 63, w = t >> 6;
  int lm = l & 15, lk = l >> 4;

  int nb = gridDim.x;
  int q8 = nb >> 3, r8 = nb & 7;
  int orig = blockIdx.x;
  int xcd = orig & 7, idx = orig >> 3;
  int wg = (xcd < r8 ? xcd * (q8 + 1) : r8 * (q8 + 1) + (xcd - r8) * q8) + idx;
  bool second = wg >= NT0;
  int tt = second ? wg - NT0 : wg;
  const u16* A = second ? A1 : A0;
  const u16* Bt = second ? Bt1 : Bt0;
  const float* bias = second ? bias1 : bias0;
  float* op = second ? out1 : out0;

  int m0 = (tt / NBY) * BM;
  int n0 = (tt % NBY) * 128;
  int wm = (w >> 1) * (BM / 2), wn = (w & 1) * 64;

  f32x4 acc[MI][4];
#pragma unroll
  for (int i = 0; i < MI; ++i)
#pragma unroll
    for (int j = 0; j < 4; ++j)
#pragma unroll
      for (int qq = 0; qq < 4; ++qq) acc[i][j][qq] = 0.0f;

  auto stage = [&](int buf, int kt) {
    int k0 = kt * 32;
    u16* As = smem + buf * BUFSZ;
    u16* Bs = As + ABUF;
    {
      int c = t;
      int row = c >> 2;
      int kc = (c & 3) ^ ((c >> 3) & 3);
      int ra = m0 + row; ra = ra < NN ? ra : NN - 1;
      const u16* ga;
      if (second)  // column-sliced X: [4][NN][64]
        ga = A + (size_t)(k0 >> 6) * NN * 64 + (size_t)ra * 64 + (k0 & 63) + kc * 8;
      else
        ga = A + (size_t)ra * K + k0 + kc * 8;
      __builtin_amdgcn_global_load_lds(
          (const __attribute__((address_space(1))) void*)ga,
          (__attribute__((address_space(3))) void*)(As + c * 8), 16, 0, 0);
    }
#pragma unroll
    for (int it = 0; it < 2; ++it) {
      int c = it * 256 + t;
      int row = c >> 2;
      int kc = (c & 3) ^ ((c >> 3) & 3);
      int rb = n0 + row; rb = rb < N ? rb : N - 1;
      const u16* gb = Bt + (size_t)rb * K + k0 + kc * 8;
      __builtin_amdgcn_global_load_lds(
          (const __attribute__((address_space(1))) void*)gb,
          (__attribute__((address_space(3))) void*)(Bs + c * 8), 16, 0, 0);
    }
  };

  int kidx = (lk ^ ((lm >> 1) & 3)) * 8;

#pragma unroll
  for (int s = 0; s < SLOTS; ++s) {
    stage(s, s);
    asm volatile("" ::: "memory");
  }
  int buf = 0;
  for (int kt = 0; kt < NK; ++kt) {
    int rem = NK - 1 - kt;
    if (rem >= 1)
      asm volatile("s_waitcnt vmcnt(%0)" ::"n"(LPT) : "memory");
    else
      asm volatile("s_waitcnt vmcnt(0)" ::: "memory");
    __builtin_amdgcn_s_barrier();
    asm volatile("" ::: "memory");
    const u16* As = smem + buf * BUFSZ;
    const u16* Bs = As + ABUF;
    short8 af[MI], bf[4];
#pragma unroll
    for (int i = 0; i < MI; ++i)
      af[i] = *reinterpret_cast<const short8*>(As + (wm + i * 16 + lm) * 32 + kidx);
#pragma unroll
    for (int j = 0; j < 4; ++j)
      bf[j] = *reinterpret_cast<const short8*>(Bs + (wn + j * 16 + lm) * 32 + kidx);
    __builtin_amdgcn_s_setprio(1);
#pragma unroll
    for (int i = 0; i < MI; ++i)
#pragma unroll
      for (int j = 0; j < 4; ++j)
        acc[i][j] = __builtin_amdgcn_mfma_f32_16x16x32_bf16(af[i], bf[j], acc[i][j], 0, 0, 0);
    __builtin_amdgcn_s_setprio(0);
    asm volatile("s_waitcnt lgkmcnt(0)" ::: "memory");
    __builtin_amdgcn_s_barrier();
    asm volatile("" ::: "memory");
    if (kt + SLOTS < NK) stage(buf, kt + SLOTS);
    buf = (buf == SLOTS - 1) ? 0 : buf + 1;
  }

#pragma unroll
  for (int j = 0; j < 4; ++j) {
    int col = n0 + wn + j * 16 + lm;
    float bv = bias[col];
#pragma unroll
    for (int i = 0; i < MI; ++i) {
      int rb = m0 + wm + i * 16 + lk * 4;
#pragma unroll
      for (int qq = 0; qq < 4; ++qq) {
        int rr = rb + qq;
        if (rr >= NN) continue;
        float v = eluf(acc[i][j][qq] + bv);
        op[(size_t)rr * N + col] = v;
      }
    }
  }
}

extern "C" void kernel_launch(void* const* d_in, const int* in_sizes, int n_in,
                              void* d_out, int out_size, void* d_ws, size_t ws_size,
                              hipStream_t stream) {
  const float* features = (const float*)d_in[0];
  const int* eidx = (const int*)d_in[1];
  const float* w1a = (const float*)d_in[2];
  const float* b1a = (const float*)d_in[3];
  const float* w1b = (const float*)d_in[4];
  const float* b1b = (const float*)d_in[5];
  const float* w2a = (const float*)d_in[6];
  const float* b2a = (const float*)d_in[7];
  const float* w2b = (const float*)d_in[8];
  const float* b2b = (const float*)d_in[9];
  const float* w3a = (const float*)d_in[10];
  const float* b3a = (const float*)d_in[11];
  const float* w3b = (const float*)d_in[12];
  const float* b3b = (const float*)d_in[13];
  const float* wr = (const float*)d_in[14];
  const float* br = (const float*)d_in[15];

  char* ws = (char*)d_ws;
  u16* bufX = (u16*)(ws);                  // sliced x: 4*NN*64*2 = 10.24 MB
  u16* bufA = (u16*)(ws + 10240000);       // activations <= 25.6 MB
  u16* bufB = (u16*)(ws + 35840000);       // activations <= 25.6 MB
  u16* wrt = (u16*)(ws + 61440000);        // transposed bf16 weights
  u16* w1at = wrt + 256 * 256;
  u16* w1bt = w1at + 640 * 256;
  u16* w2at = w1bt + 640 * 640;
  u16* w2bt = w2at + 320 * 640;
  u16* w3at = w2bt + 320 * 320;
  u16* w3bt = w3at + 256 * 320;
  int* row_start = (int*)(ws + 63700992);  // NN+1 ints (padded to 20004)
  int* cursor = row_start + 20004;         // NN ints
  int* csr_src = cursor + NN;              // NE ints
  int* counts = csr_src + NE;              // NN ints
  int* dcur = counts + NN;                 // 256 ints
  int* perm = dcur + 256;                  // NN ints

  const int* esrc = eidx;
  const int* edst = eidx + NE;

  // CSR build + prep: memset -> (prep: f2b-sliced + wt + hist) -> scan
  // (+deg-hist +dcur) -> scatter (+deg-sort perm)
  hipMemsetAsync(counts, 0, NN * sizeof(int), stream);
  k_prep<<<10523, 256, 0, stream>>>(features, bufX, edst, counts, wr, w1a, w1b,
                                    w2a, w2b, w3a, w3b, wrt, w1at, w1bt, w2at,
                                    w2bt, w3at, w3bt);
  k_scan<<<1, 1024, 0, stream>>>(counts, row_start, cursor, dcur);
  k_scatter<<<(NE + NN + 255) / 256, 256, 0, stream>>>(esrc, edst, cursor,
                                                       csr_src, counts, dcur, perm);

  float* out_x = (float*)d_out;
  float* out_res = (float*)d_out + (size_t)NN * 256;

  // L1: h0 = X + agg(X)   (gather sliced x -> normal h0)
  k_agg<256, 0><<<8 * 313, 256, 0, stream>>>(bufX, row_start, csr_src, perm, nullptr, bufA);
  // t1 = elu(h0 @ w1a + b1a)   [SLOTS=2: 5 blk/CU, single round]
  k_gemm<128, 256, 640, 1, false, false, 0, 2><<<dim3(157 * 5), 256, 0, stream>>>(bufA, w1at, b1a, bufB, NN);
  // x1 = elu(elu(t1 @ w1b + b1b))
  k_gemm<128, 640, 640, 2, false, false, 0, 2><<<dim3(157 * 5), 256, 0, stream>>>(bufB, w1bt, b1b, bufA, NN);
  // L2 (agg commuted past w2a): y2 = x1 @ w2a   [320-dim, sliced out]
  k_gemm<128, 640, 320, 0, false, false, 80, 3><<<dim3(157 * 3), 256, 0, stream>>>(bufA, w2at, nullptr, bufB, NN);
  // t2 = elu(y2 + agg(y2) + b2a)
  k_agg<320, 1><<<8 * 400, 256, 0, stream>>>(bufB, row_start, csr_src, perm, b2a, bufA);
  // x2 = elu(elu(t2 @ w2b + b2b))   [SLOTS=2: 6 blk/CU]
  k_gemm<64, 320, 320, 2, false, false, 0, 2><<<dim3(313 * 3), 256, 0, stream>>>(bufA, w2bt, b2b, bufB, NN);
  // L3 (agg commuted past w3a): y3 = x2 @ w3a   [256-dim, sliced out]
  k_gemm<64, 320, 256, 0, false, false, 64, 2><<<dim3(313 * 2), 256, 0, stream>>>(bufB, w3at, nullptr, bufA, NN);
  // t3 = elu(y3 + agg(y3) + b3a)
  k_agg<256, 1><<<8 * 313, 256, 0, stream>>>(bufA, row_start, csr_src, perm, b3a, bufB);
  // x = elu(t3 @ w3b + b3b)  AND  res = elu(X @ wr + br)  (fused dual launch)
  k_gemmd<<<dim3(626 * 2), 256, 0, stream>>>(bufB, w3bt, b3b, out_x,
                                             bufX, wrt, br, out_res);
}

// Round 13
// 248.998 us; speedup vs baseline: 1.1759x; 1.1759x over previous
//
#include <hip/hip_runtime.h>
#include <cstdint>
#include <cstddef>

#define NN 20000
#define NE 320000

typedef short short8 __attribute__((ext_vector_type(8)));
typedef float f32x4 __attribute__((ext_vector_type(4)));
typedef unsigned short u16;

__device__ __forceinline__ float b2f(u16 u) {
  union { unsigned int i; float f; } z; z.i = ((unsigned int)u) << 16; return z.f;
}
__device__ __forceinline__ u16 f2b(float f) {
  union { float f; unsigned int i; } z; z.f = f;
  unsigned int r = z.i + 0x7fffu + ((z.i >> 16) & 1u);
  return (u16)(r >> 16);
}
// fast ELU: v_exp_f32-based, not libm expm1f
__device__ __forceinline__ float eluf(float v) {
  return v > 0.0f ? v : __expf(v) - 1.0f;
}

// ------- fused prep: features f2b (column-SLICED out) + 7 weight transposes
//         + edge histogram. virtual tid space:
//         [0,1280000): f2b 4 elems ; [1280000,1600000): hist ; rest: weights.
__global__ __launch_bounds__(256) void k_prep(
    const float* __restrict__ features, u16* __restrict__ xbf_sliced,
    const int* __restrict__ edst, int* __restrict__ counts,
    const float* __restrict__ wr, const float* __restrict__ w1a,
    const float* __restrict__ w1b, const float* __restrict__ w2a,
    const float* __restrict__ w2b, const float* __restrict__ w3a,
    const float* __restrict__ w3b,
    u16* __restrict__ wrt, u16* __restrict__ w1at, u16* __restrict__ w1bt,
    u16* __restrict__ w2at, u16* __restrict__ w2bt, u16* __restrict__ w3at,
    u16* __restrict__ w3bt) {
  int tid = blockIdx.x * 256 + threadIdx.x;
  if (tid < 1280000) {
    int node = tid >> 6;
    int c4 = (tid & 63) * 4;           // col = c4..c4+3 (within one 64-slice)
    float4 v = *reinterpret_cast<const float4*>(features + (size_t)node * 256 + c4);
    ushort4 o;
    o.x = f2b(v.x); o.y = f2b(v.y); o.z = f2b(v.z); o.w = f2b(v.w);
    int slice = c4 >> 6, within = c4 & 63;
    *reinterpret_cast<ushort4*>(xbf_sliced + (size_t)slice * NN * 64 +
                                (size_t)node * 64 + within) = o;
    return;
  }
  if (tid < 1600000) {
    atomicAdd(&counts[edst[tid - 1280000]], 1);
    return;
  }
  int r = tid - 1600000;
  const float* Ws[7] = {wr, w1a, w1b, w2a, w2b, w3a, w3b};
  u16* Wts[7] = {wrt, w1at, w1bt, w2at, w2bt, w3at, w3bt};
  const int Kd[7] = {256, 256, 640, 640, 320, 320, 256};
  const int Nd[7] = {256, 640, 640, 320, 320, 256, 256};
  const int cnt[7] = {65536, 163840, 409600, 204800, 102400, 81920, 65536};
#pragma unroll
  for (int j = 0; j < 7; ++j) {
    if (r < cnt[j]) {
      int n = r / Kd[j], k = r - n * Kd[j];
      Wts[j][r] = f2b(Ws[j][(size_t)k * Nd[j] + n]);
      return;
    }
    r -= cnt[j];
  }
}

// x4-vectorized single-block scan; writes exclusive prefix to rs AND cur.
// ALSO builds the degree histogram (per-wave private LDS hists), scans it,
// and builds the degree-sorted node permutation via LDS-bin atomics (cheap:
// single-CU LDS atomics vs the R12 global-atomic version that serialized
// cross-XCD at 67us).
__global__ __launch_bounds__(1024) void k_scan(const int* __restrict__ counts,
                                               int* __restrict__ rs,
                                               int* __restrict__ cur,
                                               int* __restrict__ perm) {
  __shared__ int wsum[16];
  __shared__ int carry_s;
  __shared__ int wh[16][256];  // per-wave degree histograms
  __shared__ int sbin[256];    // scanned bin cursors
  int t = threadIdx.x;
  int l = t & 63, w = t >> 6;
  if (t == 0) carry_s = 0;
  for (int i = t; i < 16 * 256; i += 1024) ((int*)wh)[i] = 0;
  __syncthreads();
  for (int base = 0; base < NN; base += 4096) {
    int idx = base + t * 4;
    int4 v = {0, 0, 0, 0};
    if (idx < NN) {
      v = *reinterpret_cast<const int4*>(counts + idx);
      atomicAdd(&wh[w][v.x < 255 ? v.x : 255], 1);
      atomicAdd(&wh[w][v.y < 255 ? v.y : 255], 1);
      atomicAdd(&wh[w][v.z < 255 ? v.z : 255], 1);
      atomicAdd(&wh[w][v.w < 255 ? v.w : 255], 1);
    }
    int p0 = v.x, p1 = p0 + v.y, p2 = p1 + v.z, p3 = p2 + v.w;
    int incl = p3;
#pragma unroll
    for (int off = 1; off < 64; off <<= 1) {
      int u = __shfl_up(incl, off, 64);
      if (l >= off) incl += u;
    }
    if (l == 63) wsum[w] = incl;
    __syncthreads();  // (A) wsum ready
    int carry = carry_s;
    int wpre = 0;
    for (int k2 = 0; k2 < w; ++k2) wpre += wsum[k2];
    int tot = 0;
    if (t == 0)
      for (int k2 = 0; k2 < 16; ++k2) tot += wsum[k2];
    int ex = carry + wpre + incl - p3;
    if (idx < NN) {
      int4 o;
      o.x = ex; o.y = ex + p0; o.z = ex + p1; o.w = ex + p2;
      *reinterpret_cast<int4*>(rs + idx) = o;
      *reinterpret_cast<int4*>(cur + idx) = o;
    }
    __syncthreads();  // (B) all reads of wsum/carry_s done
    if (t == 0) carry_s = carry + tot;
    __syncthreads();  // (C) carry_s updated
  }
  if (t == 0) rs[NN] = carry_s;
  // ---- degree-histogram exclusive scan -> sbin (256 bins, 4 waves) ----
  __syncthreads();
  int dv = 0, incl2 = 0;
  if (t < 256) {
    int s = 0;
#pragma unroll
    for (int k2 = 0; k2 < 16; ++k2) s += wh[k2][t];
    dv = s;
    incl2 = s;
#pragma unroll
    for (int off = 1; off < 64; off <<= 1) {
      int u = __shfl_up(incl2, off, 64);
      if (l >= off) incl2 += u;
    }
    if (l == 63) wsum[w] = incl2;  // w in 0..3 here
  }
  __syncthreads();
  if (t < 256) {
    int basew = 0;
    for (int k2 = 0; k2 < w; ++k2) basew += wsum[k2];
    sbin[t] = basew + incl2 - dv;
  }
  __syncthreads();
  // ---- counting-sort scatter via LDS-bin atomics ----
  for (int base = 0; base < NN; base += 1024) {
    int nd = base + t;
    if (nd < NN) {
      int deg = counts[nd]; if (deg > 255) deg = 255;
      int p = atomicAdd(&sbin[deg], 1);
      perm[p] = nd;
    }
  }
}

// edge scatter (CSR) — R11-proven edges-only form.
__global__ __launch_bounds__(256) void k_scatter(const int* __restrict__ src,
                                                 const int* __restrict__ dst,
                                                 int* __restrict__ cursor,
                                                 int* __restrict__ csr_src, int ne) {
  int i = blockIdx.x * 256 + threadIdx.x;
  if (i >= ne) return;
  int d = dst[i];
  int p = atomicAdd(&cursor[d], 1);
  csr_src[p] = src[i];
}

// ---- aggregation, COLUMN-SLICED gather source, DEGREE-SORTED node order ----
// xs layout: [4][NN][SW] bf16 (SW = D/4). Block's slice = (blockIdx&7)&3 so
// each XCD gathers from ONE L2-resident slice. Halves take even/odd positions
// of the degree-sorted perm -> near-uniform degree within a block.
template <int D, int ACT>
__global__ __launch_bounds__(256) void k_agg(const u16* __restrict__ xs,
                                             const int* __restrict__ rs,
                                             const int* __restrict__ cs,
                                             const int* __restrict__ perm,
                                             const float* __restrict__ bias,
                                             u16* __restrict__ h) {
  constexpr int SW = D / 4;       // slice width (64 or 80 cols)
  constexpr int NCs = SW / 8;     // 16B chunks per slice-row (8 or 10)
  constexpr int NPB = 256 / NCs;  // nodes per block (32 or 25)
  int b = blockIdx.x;
  int cls = b & 7;
  int slice = cls & 3;
  int half = cls >> 2;
  int t = threadIdx.x;
  int nl = t / NCs, ch = t - nl * NCs;
  if (nl >= NPB) return;  // only when 256 % NCs != 0
  int idx2 = (b >> 3) * NPB + nl;
  if (idx2 >= 10000) return;
  int node = perm[idx2 * 2 + half];
  const u16* xp = xs + (size_t)slice * NN * SW + (size_t)ch * 8;
  float acc[8];
  {
    short8 v = *reinterpret_cast<const short8*>(xp + (size_t)node * SW);
#pragma unroll
    for (int q = 0; q < 8; ++q) acc[q] = b2f((u16)v[q]);
  }
  int e0 = rs[node], e1 = rs[node + 1];
  int e = e0;
  for (; e + 16 <= e1; e += 16) {
    int s[16];
#pragma unroll
    for (int u = 0; u < 16; ++u) s[u] = cs[e + u];
    short8 v[16];
#pragma unroll
    for (int u = 0; u < 16; ++u)
      v[u] = *reinterpret_cast<const short8*>(xp + (size_t)s[u] * SW);
#pragma unroll
    for (int q = 0; q < 8; ++q) {
      float a0 = (b2f((u16)v[0][q]) + b2f((u16)v[1][q])) +
                 (b2f((u16)v[2][q]) + b2f((u16)v[3][q]));
      float a1 = (b2f((u16)v[4][q]) + b2f((u16)v[5][q])) +
                 (b2f((u16)v[6][q]) + b2f((u16)v[7][q]));
      float a2 = (b2f((u16)v[8][q]) + b2f((u16)v[9][q])) +
                 (b2f((u16)v[10][q]) + b2f((u16)v[11][q]));
      float a3 = (b2f((u16)v[12][q]) + b2f((u16)v[13][q])) +
                 (b2f((u16)v[14][q]) + b2f((u16)v[15][q]));
      acc[q] += (a0 + a1) + (a2 + a3);
    }
  }
  for (; e + 8 <= e1; e += 8) {
    int s[8];
#pragma unroll
    for (int u = 0; u < 8; ++u) s[u] = cs[e + u];
    short8 v[8];
#pragma unroll
    for (int u = 0; u < 8; ++u)
      v[u] = *reinterpret_cast<const short8*>(xp + (size_t)s[u] * SW);
#pragma unroll
    for (int q = 0; q < 8; ++q) {
      float a0 = b2f((u16)v[0][q]) + b2f((u16)v[1][q]);
      float a1 = b2f((u16)v[2][q]) + b2f((u16)v[3][q]);
      float a2 = b2f((u16)v[4][q]) + b2f((u16)v[5][q]);
      float a3 = b2f((u16)v[6][q]) + b2f((u16)v[7][q]);
      acc[q] += (a0 + a1) + (a2 + a3);
    }
  }
  for (; e + 4 <= e1; e += 4) {
    int s0 = cs[e], s1 = cs[e + 1], s2 = cs[e + 2], s3 = cs[e + 3];
    short8 v0 = *reinterpret_cast<const short8*>(xp + (size_t)s0 * SW);
    short8 v1 = *reinterpret_cast<const short8*>(xp + (size_t)s1 * SW);
    short8 v2 = *reinterpret_cast<const short8*>(xp + (size_t)s2 * SW);
    short8 v3 = *reinterpret_cast<const short8*>(xp + (size_t)s3 * SW);
#pragma unroll
    for (int q = 0; q < 8; ++q)
      acc[q] += (b2f((u16)v0[q]) + b2f((u16)v1[q])) + (b2f((u16)v2[q]) + b2f((u16)v3[q]));
  }
  for (; e < e1; ++e) {
    int s = cs[e];
    short8 v = *reinterpret_cast<const short8*>(xp + (size_t)s * SW);
#pragma unroll
    for (int q = 0; q < 8; ++q) acc[q] += b2f((u16)v[q]);
  }
  int col0 = slice * SW + ch * 8;
  if (ACT == 1) {
    float4 b0 = *reinterpret_cast<const float4*>(bias + col0);
    float4 b1 = *reinterpret_cast<const float4*>(bias + col0 + 4);
    acc[0] = eluf(acc[0] + b0.x); acc[1] = eluf(acc[1] + b0.y);
    acc[2] = eluf(acc[2] + b0.z); acc[3] = eluf(acc[3] + b0.w);
    acc[4] = eluf(acc[4] + b1.x); acc[5] = eluf(acc[5] + b1.y);
    acc[6] = eluf(acc[6] + b1.z); acc[7] = eluf(acc[7] + b1.w);
  }
  short8 o;
#pragma unroll
  for (int q = 0; q < 8; ++q) o[q] = (short)f2b(acc[q]);
  *reinterpret_cast<short8*>(h + (size_t)node * D + col0) = o;
}

// ---------------- GEMM: C = act(A[M][K] @ B[K][N] + bias) ----------------
// BMx128 tile, BK=32, SLOTS-deep prefetch ring with counted vmcnt + raw
// s_barrier, issue-order fences, setprio around MFMA, 4 waves, 16x16x32 bf16
// MFMA, swizzled LDS, XCD-chunked grid.
template <int BM, int K, int N, int ACT, bool OUTF32, bool INS, int OSW, int SLOTS>
__global__ __launch_bounds__(256) void k_gemm(const u16* __restrict__ A,
                                              const u16* __restrict__ Bt,
                                              const float* __restrict__ bias,
                                              void* __restrict__ outp, int M) {
  constexpr int NBY = (N + 127) / 128;
  constexpr int NK = K / 32;
  constexpr int ABUF = BM * 32;       // u16 per A LDS buffer
  constexpr int BUFSZ = ABUF + 4096;  // A + B per ring slot
  constexpr int MI = BM / 32;         // acc i-extent per wave (2 or 4)
  constexpr int LPT = BM / 64 + 2;    // global_load_lds per thread per stage
  __shared__ __align__(16) u16 smem[SLOTS * BUFSZ];
  int t = threadIdx.x;
  int l = t & 63, w = t >> 6;
  int lm = l & 15, lk = l >> 4;

  // bijective XCD-chunked swizzle (m204)
  int nb = gridDim.x;
  int q8 = nb >> 3, r8 = nb & 7;
  int orig = blockIdx.x;
  int xcd = orig & 7, idx = orig >> 3;
  int wg = (xcd < r8 ? xcd * (q8 + 1) : r8 * (q8 + 1) + (xcd - r8) * q8) + idx;
  int m0 = (wg / NBY) * BM;
  int n0 = (wg % NBY) * 128;
  int wm = (w >> 1) * (BM / 2), wn = (w & 1) * 64;

  f32x4 acc[MI][4];
#pragma unroll
  for (int i = 0; i < MI; ++i)
#pragma unroll
    for (int j = 0; j < 4; ++j)
#pragma unroll
      for (int qq = 0; qq < 4; ++qq) acc[i][j][qq] = 0.0f;

  auto stage = [&](int buf, int kt) {
    int k0 = kt * 32;
    u16* As = smem + buf * BUFSZ;
    u16* Bs = As + ABUF;
#pragma unroll
    for (int it = 0; it < BM / 64; ++it) {  // A
      int c = it * 256 + t;
      int row = c >> 2;
      int kc = (c & 3) ^ ((c >> 3) & 3);
      int ra = m0 + row; ra = ra < M ? ra : M - 1;
      const u16* ga;
      if (INS)
        ga = A + (size_t)(k0 >> 6) * NN * 64 + (size_t)ra * 64 + (k0 & 63) + kc * 8;
      else
        ga = A + (size_t)ra * K + k0 + kc * 8;
      __builtin_amdgcn_global_load_lds(
          (const __attribute__((address_space(1))) void*)ga,
          (__attribute__((address_space(3))) void*)(As + c * 8), 16, 0, 0);
    }
#pragma unroll
    for (int it = 0; it < 2; ++it) {        // B: 128*32 u16
      int c = it * 256 + t;
      int row = c >> 2;
      int kc = (c & 3) ^ ((c >> 3) & 3);
      int rb = n0 + row; rb = rb < N ? rb : N - 1;
      const u16* gb = Bt + (size_t)rb * K + k0 + kc * 8;
      __builtin_amdgcn_global_load_lds(
          (const __attribute__((address_space(1))) void*)gb,
          (__attribute__((address_space(3))) void*)(Bs + c * 8), 16, 0, 0);
    }
  };

  int kidx = (lk ^ ((lm >> 1) & 3)) * 8;

#pragma unroll
  for (int s = 0; s < SLOTS; ++s) {
    stage(s, s);
    asm volatile("" ::: "memory");
  }
  int buf = 0;
  for (int kt = 0; kt < NK; ++kt) {
    int rem = NK - 1 - kt;
    if (SLOTS == 3) {
      if (rem >= 2)
        asm volatile("s_waitcnt vmcnt(%0)" ::"n"(2 * LPT) : "memory");
      else if (rem == 1)
        asm volatile("s_waitcnt vmcnt(%0)" ::"n"(LPT) : "memory");
      else
        asm volatile("s_waitcnt vmcnt(0)" ::: "memory");
    } else {
      if (rem >= 1)
        asm volatile("s_waitcnt vmcnt(%0)" ::"n"(LPT) : "memory");
      else
        asm volatile("s_waitcnt vmcnt(0)" ::: "memory");
    }
    __builtin_amdgcn_s_barrier();
    asm volatile("" ::: "memory");
    const u16* As = smem + buf * BUFSZ;
    const u16* Bs = As + ABUF;
    short8 af[MI], bf[4];
#pragma unroll
    for (int i = 0; i < MI; ++i)
      af[i] = *reinterpret_cast<const short8*>(As + (wm + i * 16 + lm) * 32 + kidx);
#pragma unroll
    for (int j = 0; j < 4; ++j)
      bf[j] = *reinterpret_cast<const short8*>(Bs + (wn + j * 16 + lm) * 32 + kidx);
    __builtin_amdgcn_s_setprio(1);
#pragma unroll
    for (int i = 0; i < MI; ++i)
#pragma unroll
      for (int j = 0; j < 4; ++j)
        acc[i][j] = __builtin_amdgcn_mfma_f32_16x16x32_bf16(af[i], bf[j], acc[i][j], 0, 0, 0);
    __builtin_amdgcn_s_setprio(0);
    asm volatile("s_waitcnt lgkmcnt(0)" ::: "memory");
    __builtin_amdgcn_s_barrier();
    asm volatile("" ::: "memory");
    if (kt + SLOTS < NK) stage(buf, kt + SLOTS);
    buf = (buf == SLOTS - 1) ? 0 : buf + 1;
  }

  // epilogue. C/D frag layout: row = i*16 + lk*4 + qq, col = j*16 + lm.
  if (!OUTF32) {
    u16* ep = smem + w * (BM / 2) * 64;
#pragma unroll
    for (int j = 0; j < 4; ++j) {
      int col = n0 + wn + j * 16 + lm;
      float bv = (ACT > 0) ? bias[col < N ? col : N - 1] : 0.0f;
#pragma unroll
      for (int i = 0; i < MI; ++i)
#pragma unroll
        for (int qq = 0; qq < 4; ++qq) {
          float v = acc[i][j][qq];
          if (ACT > 0) { v += bv; v = eluf(v); }
          if (ACT == 2) v = eluf(v);
          ep[(i * 16 + lk * 4 + qq) * 64 + j * 16 + lm] = f2b(v);
        }
    }
    __syncthreads();
    u16* op = (u16*)outp;
#pragma unroll
    for (int u = 0; u < BM / 16; ++u) {
      int rrow = m0 + wm + u * 8 + (l >> 3);
      int col = n0 + wn + (l & 7) * 8;
      if (rrow < M && col < N) {
        short8 val = *reinterpret_cast<const short8*>(ep + u * 512 + l * 8);
        if (OSW) {
          int slice = col / OSW, within = col - slice * OSW;
          *reinterpret_cast<short8*>(op + (size_t)slice * NN * OSW +
                                     (size_t)rrow * OSW + within) = val;
        } else {
          *reinterpret_cast<short8*>(op + (size_t)rrow * N + col) = val;
        }
      }
    }
  } else {
    float* op = (float*)outp;
#pragma unroll
    for (int j = 0; j < 4; ++j) {
      int col = n0 + wn + j * 16 + lm;
      if (col >= N) continue;
      float bv = (ACT > 0) ? bias[col] : 0.0f;
#pragma unroll
      for (int i = 0; i < MI; ++i) {
        int rb = m0 + wm + i * 16 + lk * 4;
#pragma unroll
        for (int qq = 0; qq < 4; ++qq) {
          int rr = rb + qq;
          if (rr >= M) continue;
          float v = acc[i][j][qq];
          if (ACT > 0) { v += bv; v = eluf(v); }
          if (ACT == 2) v = eluf(v);
          op[(size_t)rr * N + col] = v;
        }
      }
    }
  }
}

// ---- DUAL GEMM: two independent K=256,N=256,BM=64,ACT=1,fp32-out GEMMs in
// one launch (x tiles [0,NT0), res tiles [NT0,2*NT0); res reads sliced X).
__global__ __launch_bounds__(256) void k_gemmd(
    const u16* __restrict__ A0, const u16* __restrict__ Bt0,
    const float* __restrict__ bias0, float* __restrict__ out0,
    const u16* __restrict__ A1, const u16* __restrict__ Bt1,
    const float* __restrict__ bias1, float* __restrict__ out1) {
  constexpr int K = 256, N = 256, BM = 64;
  constexpr int NBY = 2, NK = 8, NT0 = 626;
  constexpr int ABUF = BM * 32, BUFSZ = ABUF + 4096, MI = 2, LPT = 3;
  constexpr int SLOTS = 2;  // 24KB -> 6 blk/CU; grid 1252 <= 1536 single round
  __shared__ __align__(16) u16 smem[SLOTS * BUFSZ];
  int t = threadIdx.x;
  int l = t & 63, w = t >> 6;
  int lm = l & 15, lk = l >> 4;

  int nb = gridDim.x;
  int q8 = nb >> 3, r8 = nb & 7;
  int orig = blockIdx.x;
  int xcd = orig & 7, idx = orig >> 3;
  int wg = (xcd < r8 ? xcd * (q8 + 1) : r8 * (q8 + 1) + (xcd - r8) * q8) + idx;
  bool second = wg >= NT0;
  int tt = second ? wg - NT0 : wg;
  const u16* A = second ? A1 : A0;
  const u16* Bt = second ? Bt1 : Bt0;
  const float* bias = second ? bias1 : bias0;
  float* op = second ? out1 : out0;

  int m0 = (tt / NBY) * BM;
  int n0 = (tt % NBY) * 128;
  int wm = (w >> 1) * (BM / 2), wn = (w & 1) * 64;

  f32x4 acc[MI][4];
#pragma unroll
  for (int i = 0; i < MI; ++i)
#pragma unroll
    for (int j = 0; j < 4; ++j)
#pragma unroll
      for (int qq = 0; qq < 4; ++qq) acc[i][j][qq] = 0.0f;

  auto stage = [&](int buf, int kt) {
    int k0 = kt * 32;
    u16* As = smem + buf * BUFSZ;
    u16* Bs = As + ABUF;
    {
      int c = t;
      int row = c >> 2;
      int kc = (c & 3) ^ ((c >> 3) & 3);
      int ra = m0 + row; ra = ra < NN ? ra : NN - 1;
      const u16* ga;
      if (second)  // column-sliced X: [4][NN][64]
        ga = A + (size_t)(k0 >> 6) * NN * 64 + (size_t)ra * 64 + (k0 & 63) + kc * 8;
      else
        ga = A + (size_t)ra * K + k0 + kc * 8;
      __builtin_amdgcn_global_load_lds(
          (const __attribute__((address_space(1))) void*)ga,
          (__attribute__((address_space(3))) void*)(As + c * 8), 16, 0, 0);
    }
#pragma unroll
    for (int it = 0; it < 2; ++it) {
      int c = it * 256 + t;
      int row = c >> 2;
      int kc = (c & 3) ^ ((c >> 3) & 3);
      int rb = n0 + row; rb = rb < N ? rb : N - 1;
      const u16* gb = Bt + (size_t)rb * K + k0 + kc * 8;
      __builtin_amdgcn_global_load_lds(
          (const __attribute__((address_space(1))) void*)gb,
          (__attribute__((address_space(3))) void*)(Bs + c * 8), 16, 0, 0);
    }
  };

  int kidx = (lk ^ ((lm >> 1) & 3)) * 8;

#pragma unroll
  for (int s = 0; s < SLOTS; ++s) {
    stage(s, s);
    asm volatile("" ::: "memory");
  }
  int buf = 0;
  for (int kt = 0; kt < NK; ++kt) {
    int rem = NK - 1 - kt;
    if (rem >= 1)
      asm volatile("s_waitcnt vmcnt(%0)" ::"n"(LPT) : "memory");
    else
      asm volatile("s_waitcnt vmcnt(0)" ::: "memory");
    __builtin_amdgcn_s_barrier();
    asm volatile("" ::: "memory");
    const u16* As = smem + buf * BUFSZ;
    const u16* Bs = As + ABUF;
    short8 af[MI], bf[4];
#pragma unroll
    for (int i = 0; i < MI; ++i)
      af[i] = *reinterpret_cast<const short8*>(As + (wm + i * 16 + lm) * 32 + kidx);
#pragma unroll
    for (int j = 0; j < 4; ++j)
      bf[j] = *reinterpret_cast<const short8*>(Bs + (wn + j * 16 + lm) * 32 + kidx);
    __builtin_amdgcn_s_setprio(1);
#pragma unroll
    for (int i = 0; i < MI; ++i)
#pragma unroll
      for (int j = 0; j < 4; ++j)
        acc[i][j] = __builtin_amdgcn_mfma_f32_16x16x32_bf16(af[i], bf[j], acc[i][j], 0, 0, 0);
    __builtin_amdgcn_s_setprio(0);
    asm volatile("s_waitcnt lgkmcnt(0)" ::: "memory");
    __builtin_amdgcn_s_barrier();
    asm volatile("" ::: "memory");
    if (kt + SLOTS < NK) stage(buf, kt + SLOTS);
    buf = (buf == SLOTS - 1) ? 0 : buf + 1;
  }

#pragma unroll
  for (int j = 0; j < 4; ++j) {
    int col = n0 + wn + j * 16 + lm;
    float bv = bias[col];
#pragma unroll
    for (int i = 0; i < MI; ++i) {
      int rb = m0 + wm + i * 16 + lk * 4;
#pragma unroll
      for (int qq = 0; qq < 4; ++qq) {
        int rr = rb + qq;
        if (rr >= NN) continue;
        float v = eluf(acc[i][j][qq] + bv);
        op[(size_t)rr * N + col] = v;
      }
    }
  }
}

extern "C" void kernel_launch(void* const* d_in, const int* in_sizes, int n_in,
                              void* d_out, int out_size, void* d_ws, size_t ws_size,
                              hipStream_t stream) {
  const float* features = (const float*)d_in[0];
  const int* eidx = (const int*)d_in[1];
  const float* w1a = (const float*)d_in[2];
  const float* b1a = (const float*)d_in[3];
  const float* w1b = (const float*)d_in[4];
  const float* b1b = (const float*)d_in[5];
  const float* w2a = (const float*)d_in[6];
  const float* b2a = (const float*)d_in[7];
  const float* w2b = (const float*)d_in[8];
  const float* b2b = (const float*)d_in[9];
  const float* w3a = (const float*)d_in[10];
  const float* b3a = (const float*)d_in[11];
  const float* w3b = (const float*)d_in[12];
  const float* b3b = (const float*)d_in[13];
  const float* wr = (const float*)d_in[14];
  const float* br = (const float*)d_in[15];

  char* ws = (char*)d_ws;
  u16* bufX = (u16*)(ws);                  // sliced x: 4*NN*64*2 = 10.24 MB
  u16* bufA = (u16*)(ws + 10240000);       // activations <= 25.6 MB
  u16* bufB = (u16*)(ws + 35840000);       // activations <= 25.6 MB
  u16* wrt = (u16*)(ws + 61440000);        // transposed bf16 weights
  u16* w1at = wrt + 256 * 256;
  u16* w1bt = w1at + 640 * 256;
  u16* w2at = w1bt + 640 * 640;
  u16* w2bt = w2at + 320 * 640;
  u16* w3at = w2bt + 320 * 320;
  u16* w3bt = w3at + 256 * 320;
  int* row_start = (int*)(ws + 63700992);  // NN+1 ints (padded to 20004)
  int* cursor = row_start + 20004;         // NN ints
  int* csr_src = cursor + NN;              // NE ints
  int* counts = csr_src + NE;              // NN ints
  int* perm = counts + NN;                 // NN ints

  const int* esrc = eidx;
  const int* edst = eidx + NE;

  // CSR build + prep: memset -> (prep: f2b-sliced + wt + hist) -> scan
  // (+deg-hist +perm build via LDS-bin atomics) -> scatter (edges only)
  hipMemsetAsync(counts, 0, NN * sizeof(int), stream);
  k_prep<<<10523, 256, 0, stream>>>(features, bufX, edst, counts, wr, w1a, w1b,
                                    w2a, w2b, w3a, w3b, wrt, w1at, w1bt, w2at,
                                    w2bt, w3at, w3bt);
  k_scan<<<1, 1024, 0, stream>>>(counts, row_start, cursor, perm);
  k_scatter<<<(NE + 255) / 256, 256, 0, stream>>>(esrc, edst, cursor, csr_src, NE);

  float* out_x = (float*)d_out;
  float* out_res = (float*)d_out + (size_t)NN * 256;

  // L1: h0 = X + agg(X)   (gather sliced x -> normal h0)
  k_agg<256, 0><<<8 * 313, 256, 0, stream>>>(bufX, row_start, csr_src, perm, nullptr, bufA);
  // t1 = elu(h0 @ w1a + b1a)   [SLOTS=2: 5 blk/CU, single round]
  k_gemm<128, 256, 640, 1, false, false, 0, 2><<<dim3(157 * 5), 256, 0, stream>>>(bufA, w1at, b1a, bufB, NN);
  // x1 = elu(elu(t1 @ w1b + b1b))
  k_gemm<128, 640, 640, 2, false, false, 0, 2><<<dim3(157 * 5), 256, 0, stream>>>(bufB, w1bt, b1b, bufA, NN);
  // L2 (agg commuted past w2a): y2 = x1 @ w2a   [320-dim, sliced out]
  k_gemm<128, 640, 320, 0, false, false, 80, 3><<<dim3(157 * 3), 256, 0, stream>>>(bufA, w2at, nullptr, bufB, NN);
  // t2 = elu(y2 + agg(y2) + b2a)
  k_agg<320, 1><<<8 * 400, 256, 0, stream>>>(bufB, row_start, csr_src, perm, b2a, bufA);
  // x2 = elu(elu(t2 @ w2b + b2b))   [SLOTS=2: 6 blk/CU]
  k_gemm<64, 320, 320, 2, false, false, 0, 2><<<dim3(313 * 3), 256, 0, stream>>>(bufA, w2bt, b2b, bufB, NN);
  // L3 (agg commuted past w3a): y3 = x2 @ w3a   [256-dim, sliced out]
  k_gemm<64, 320, 256, 0, false, false, 64, 2><<<dim3(313 * 2), 256, 0, stream>>>(bufB, w3at, nullptr, bufA, NN);
  // t3 = elu(y3 + agg(y3) + b3a)
  k_agg<256, 1><<<8 * 313, 256, 0, stream>>>(bufA, row_start, csr_src, perm, b3a, bufB);
  // x = elu(t3 @ w3b + b3b)  AND  res = elu(X @ wr + br)  (fused dual launch)
  k_gemmd<<<dim3(626 * 2), 256, 0, stream>>>(bufB, w3bt, b3b, out_x,
                                             bufX, wrt, br, out_res);
}

// Round 14
// 246.819 us; speedup vs baseline: 1.1863x; 1.0088x over previous
//
#include <hip/hip_runtime.h>
#include <cstdint>
#include <cstddef>

#define NN 20000
#define NE 320000

typedef short short8 __attribute__((ext_vector_type(8)));
typedef float f32x4 __attribute__((ext_vector_type(4)));
typedef unsigned short u16;

__device__ __forceinline__ float b2f(u16 u) {
  union { unsigned int i; float f; } z; z.i = ((unsigned int)u) << 16; return z.f;
}
__device__ __forceinline__ u16 f2b(float f) {
  union { float f; unsigned int i; } z; z.f = f;
  unsigned int r = z.i + 0x7fffu + ((z.i >> 16) & 1u);
  return (u16)(r >> 16);
}
// fast ELU: v_exp_f32-based, not libm expm1f
__device__ __forceinline__ float eluf(float v) {
  return v > 0.0f ? v : __expf(v) - 1.0f;
}

// ------- fused prep: features f2b (8-way column-SLICED out) + 7 weight
//         transposes + edge histogram. virtual tid space:
//         [0,1280000): f2b 4 elems ; [1280000,1600000): hist ; rest: weights.
__global__ __launch_bounds__(256) void k_prep(
    const float* __restrict__ features, u16* __restrict__ xbf_sliced,
    const int* __restrict__ edst, int* __restrict__ counts,
    const float* __restrict__ wr, const float* __restrict__ w1a,
    const float* __restrict__ w1b, const float* __restrict__ w2a,
    const float* __restrict__ w2b, const float* __restrict__ w3a,
    const float* __restrict__ w3b,
    u16* __restrict__ wrt, u16* __restrict__ w1at, u16* __restrict__ w1bt,
    u16* __restrict__ w2at, u16* __restrict__ w2bt, u16* __restrict__ w3at,
    u16* __restrict__ w3bt) {
  int tid = blockIdx.x * 256 + threadIdx.x;
  if (tid < 1280000) {
    int node = tid >> 6;
    int c4 = (tid & 63) * 4;           // col = c4..c4+3 (within one 32-slice)
    float4 v = *reinterpret_cast<const float4*>(features + (size_t)node * 256 + c4);
    ushort4 o;
    o.x = f2b(v.x); o.y = f2b(v.y); o.z = f2b(v.z); o.w = f2b(v.w);
    int slice = c4 >> 5, within = c4 & 31;   // 8 slices of 32 cols
    *reinterpret_cast<ushort4*>(xbf_sliced + (size_t)slice * NN * 32 +
                                (size_t)node * 32 + within) = o;
    return;
  }
  if (tid < 1600000) {
    atomicAdd(&counts[edst[tid - 1280000]], 1);
    return;
  }
  int r = tid - 1600000;
  const float* Ws[7] = {wr, w1a, w1b, w2a, w2b, w3a, w3b};
  u16* Wts[7] = {wrt, w1at, w1bt, w2at, w2bt, w3at, w3bt};
  const int Kd[7] = {256, 256, 640, 640, 320, 320, 256};
  const int Nd[7] = {256, 640, 640, 320, 320, 256, 256};
  const int cnt[7] = {65536, 163840, 409600, 204800, 102400, 81920, 65536};
#pragma unroll
  for (int j = 0; j < 7; ++j) {
    if (r < cnt[j]) {
      int n = r / Kd[j], k = r - n * Kd[j];
      Wts[j][r] = f2b(Ws[j][(size_t)k * Nd[j] + n]);
      return;
    }
    r -= cnt[j];
  }
}

// x4-vectorized single-block scan; writes exclusive prefix to BOTH rs and cur.
// (R11-proven version — degree-sort removed: net-negative, R12/R13.)
__global__ __launch_bounds__(1024) void k_scan(const int* __restrict__ counts,
                                               int* __restrict__ rs,
                                               int* __restrict__ cur) {
  __shared__ int wsum[16];
  __shared__ int carry_s;
  int t = threadIdx.x;
  int l = t & 63, w = t >> 6;
  if (t == 0) carry_s = 0;
  __syncthreads();
  for (int base = 0; base < NN; base += 4096) {
    int idx = base + t * 4;
    int4 v = {0, 0, 0, 0};
    if (idx < NN) v = *reinterpret_cast<const int4*>(counts + idx);
    int p0 = v.x, p1 = p0 + v.y, p2 = p1 + v.z, p3 = p2 + v.w;
    int incl = p3;
#pragma unroll
    for (int off = 1; off < 64; off <<= 1) {
      int u = __shfl_up(incl, off, 64);
      if (l >= off) incl += u;
    }
    if (l == 63) wsum[w] = incl;
    __syncthreads();  // (A) wsum ready
    int carry = carry_s;
    int wpre = 0;
    for (int k2 = 0; k2 < w; ++k2) wpre += wsum[k2];
    int tot = 0;
    if (t == 0)
      for (int k2 = 0; k2 < 16; ++k2) tot += wsum[k2];
    int ex = carry + wpre + incl - p3;
    if (idx < NN) {
      int4 o;
      o.x = ex; o.y = ex + p0; o.z = ex + p1; o.w = ex + p2;
      *reinterpret_cast<int4*>(rs + idx) = o;
      *reinterpret_cast<int4*>(cur + idx) = o;
    }
    __syncthreads();  // (B) all reads of wsum/carry_s done
    if (t == 0) carry_s = carry + tot;
    __syncthreads();  // (C) carry_s updated
  }
  if (t == 0) rs[NN] = carry_s;
}

// edge scatter (CSR) — R11-proven edges-only form.
__global__ __launch_bounds__(256) void k_scatter(const int* __restrict__ src,
                                                 const int* __restrict__ dst,
                                                 int* __restrict__ cursor,
                                                 int* __restrict__ csr_src, int ne) {
  int i = blockIdx.x * 256 + threadIdx.x;
  if (i >= ne) return;
  int d = dst[i];
  int p = atomicAdd(&cursor[d], 1);
  csr_src[p] = src[i];
}

// ---- aggregation, 8-way COLUMN-SLICED gather source ------------------------
// xs layout: [8][NN][SW] bf16 (SW = D/8). Block's slice = blockIdx&7 so —
// under round-robin blockIdx->XCD dispatch — each XCD-class owns exactly ONE
// 1.28-1.6MB slice: HBM fetch per agg halves vs the 4-slice/2-class scheme
// and per-XCD L2 footprint halves. Each class sweeps all NN nodes.
// Output h is NORMAL [NN][D]. ACT=0: identity; ACT=1: elu(v+bias).
template <int D, int ACT>
__global__ __launch_bounds__(256) void k_agg(const u16* __restrict__ xs,
                                             const int* __restrict__ rs,
                                             const int* __restrict__ cs,
                                             const float* __restrict__ bias,
                                             u16* __restrict__ h) {
  constexpr int SW = D / 8;       // slice width (32 or 40 cols)
  constexpr int NCs = SW / 8;     // 16B chunks per slice-row (4 or 5)
  constexpr int NPB = 256 / NCs;  // nodes per block (64 or 51)
  int b = blockIdx.x;
  int slice = b & 7;
  int t = threadIdx.x;
  int nl = t / NCs, ch = t - nl * NCs;
  if (nl >= NPB) return;  // only when 256 % NCs != 0
  int node = (b >> 3) * NPB + nl;
  if (node >= NN) return;
  const u16* xp = xs + (size_t)slice * NN * SW + (size_t)ch * 8;
  float acc[8];
  {
    short8 v = *reinterpret_cast<const short8*>(xp + (size_t)node * SW);
#pragma unroll
    for (int q = 0; q < 8; ++q) acc[q] = b2f((u16)v[q]);
  }
  int e0 = rs[node], e1 = rs[node + 1];
  int e = e0;
  // 16-wide unroll: 16 independent gathers in flight (latency-bound loop)
  for (; e + 16 <= e1; e += 16) {
    int s[16];
#pragma unroll
    for (int u = 0; u < 16; ++u) s[u] = cs[e + u];
    short8 v[16];
#pragma unroll
    for (int u = 0; u < 16; ++u)
      v[u] = *reinterpret_cast<const short8*>(xp + (size_t)s[u] * SW);
#pragma unroll
    for (int q = 0; q < 8; ++q) {
      float a0 = (b2f((u16)v[0][q]) + b2f((u16)v[1][q])) +
                 (b2f((u16)v[2][q]) + b2f((u16)v[3][q]));
      float a1 = (b2f((u16)v[4][q]) + b2f((u16)v[5][q])) +
                 (b2f((u16)v[6][q]) + b2f((u16)v[7][q]));
      float a2 = (b2f((u16)v[8][q]) + b2f((u16)v[9][q])) +
                 (b2f((u16)v[10][q]) + b2f((u16)v[11][q]));
      float a3 = (b2f((u16)v[12][q]) + b2f((u16)v[13][q])) +
                 (b2f((u16)v[14][q]) + b2f((u16)v[15][q]));
      acc[q] += (a0 + a1) + (a2 + a3);
    }
  }
  for (; e + 8 <= e1; e += 8) {
    int s[8];
#pragma unroll
    for (int u = 0; u < 8; ++u) s[u] = cs[e + u];
    short8 v[8];
#pragma unroll
    for (int u = 0; u < 8; ++u)
      v[u] = *reinterpret_cast<const short8*>(xp + (size_t)s[u] * SW);
#pragma unroll
    for (int q = 0; q < 8; ++q) {
      float a0 = b2f((u16)v[0][q]) + b2f((u16)v[1][q]);
      float a1 = b2f((u16)v[2][q]) + b2f((u16)v[3][q]);
      float a2 = b2f((u16)v[4][q]) + b2f((u16)v[5][q]);
      float a3 = b2f((u16)v[6][q]) + b2f((u16)v[7][q]);
      acc[q] += (a0 + a1) + (a2 + a3);
    }
  }
  for (; e + 4 <= e1; e += 4) {
    int s0 = cs[e], s1 = cs[e + 1], s2 = cs[e + 2], s3 = cs[e + 3];
    short8 v0 = *reinterpret_cast<const short8*>(xp + (size_t)s0 * SW);
    short8 v1 = *reinterpret_cast<const short8*>(xp + (size_t)s1 * SW);
    short8 v2 = *reinterpret_cast<const short8*>(xp + (size_t)s2 * SW);
    short8 v3 = *reinterpret_cast<const short8*>(xp + (size_t)s3 * SW);
#pragma unroll
    for (int q = 0; q < 8; ++q)
      acc[q] += (b2f((u16)v0[q]) + b2f((u16)v1[q])) + (b2f((u16)v2[q]) + b2f((u16)v3[q]));
  }
  for (; e < e1; ++e) {
    int s = cs[e];
    short8 v = *reinterpret_cast<const short8*>(xp + (size_t)s * SW);
#pragma unroll
    for (int q = 0; q < 8; ++q) acc[q] += b2f((u16)v[q]);
  }
  int col0 = slice * SW + ch * 8;
  if (ACT == 1) {
    float4 b0 = *reinterpret_cast<const float4*>(bias + col0);
    float4 b1 = *reinterpret_cast<const float4*>(bias + col0 + 4);
    acc[0] = eluf(acc[0] + b0.x); acc[1] = eluf(acc[1] + b0.y);
    acc[2] = eluf(acc[2] + b0.z); acc[3] = eluf(acc[3] + b0.w);
    acc[4] = eluf(acc[4] + b1.x); acc[5] = eluf(acc[5] + b1.y);
    acc[6] = eluf(acc[6] + b1.z); acc[7] = eluf(acc[7] + b1.w);
  }
  short8 o;
#pragma unroll
  for (int q = 0; q < 8; ++q) o[q] = (short)f2b(acc[q]);
  *reinterpret_cast<short8*>(h + (size_t)node * D + col0) = o;
}

// ---------------- GEMM: C = act(A[M][K] @ B[K][N] + bias) ----------------
// A bf16 [M][K] (or 8-way column-sliced [8][M][32] when INS), Bt bf16 [N][K].
// BMx128 tile, BK=32, SLOTS-deep prefetch ring with counted vmcnt + raw
// s_barrier, issue-order fences, setprio around MFMA, 4 waves, 16x16x32 bf16
// MFMA, swizzled LDS, XCD-chunked grid.
// OSW: 0 = normal [M][N] out; else 8-way column-sliced [8][M][OSW] bf16 out.
template <int BM, int K, int N, int ACT, bool OUTF32, bool INS, int OSW, int SLOTS>
__global__ __launch_bounds__(256) void k_gemm(const u16* __restrict__ A,
                                              const u16* __restrict__ Bt,
                                              const float* __restrict__ bias,
                                              void* __restrict__ outp, int M) {
  constexpr int NBY = (N + 127) / 128;
  constexpr int NK = K / 32;
  constexpr int ABUF = BM * 32;       // u16 per A LDS buffer
  constexpr int BUFSZ = ABUF + 4096;  // A + B per ring slot
  constexpr int MI = BM / 32;         // acc i-extent per wave (2 or 4)
  constexpr int LPT = BM / 64 + 2;    // global_load_lds per thread per stage
  __shared__ __align__(16) u16 smem[SLOTS * BUFSZ];
  int t = threadIdx.x;
  int l = t & 63, w = t >> 6;
  int lm = l & 15, lk = l >> 4;

  // bijective XCD-chunked swizzle (m204)
  int nb = gridDim.x;
  int q8 = nb >> 3, r8 = nb & 7;
  int orig = blockIdx.x;
  int xcd = orig & 7, idx = orig >> 3;
  int wg = (xcd < r8 ? xcd * (q8 + 1) : r8 * (q8 + 1) + (xcd - r8) * q8) + idx;
  int m0 = (wg / NBY) * BM;
  int n0 = (wg % NBY) * 128;
  int wm = (w >> 1) * (BM / 2), wn = (w & 1) * 64;

  f32x4 acc[MI][4];
#pragma unroll
  for (int i = 0; i < MI; ++i)
#pragma unroll
    for (int j = 0; j < 4; ++j)
#pragma unroll
      for (int qq = 0; qq < 4; ++qq) acc[i][j][qq] = 0.0f;

  auto stage = [&](int buf, int kt) {
    int k0 = kt * 32;
    u16* As = smem + buf * BUFSZ;
    u16* Bs = As + ABUF;
#pragma unroll
    for (int it = 0; it < BM / 64; ++it) {  // A
      int c = it * 256 + t;
      int row = c >> 2;
      int kc = (c & 3) ^ ((c >> 3) & 3);
      int ra = m0 + row; ra = ra < M ? ra : M - 1;
      const u16* ga;
      if (INS)  // 8-way sliced A: [8][M][32]; 32-col K-chunk = one slice
        ga = A + (size_t)(k0 >> 5) * NN * 32 + (size_t)ra * 32 + kc * 8;
      else
        ga = A + (size_t)ra * K + k0 + kc * 8;
      __builtin_amdgcn_global_load_lds(
          (const __attribute__((address_space(1))) void*)ga,
          (__attribute__((address_space(3))) void*)(As + c * 8), 16, 0, 0);
    }
#pragma unroll
    for (int it = 0; it < 2; ++it) {        // B: 128*32 u16
      int c = it * 256 + t;
      int row = c >> 2;
      int kc = (c & 3) ^ ((c >> 3) & 3);
      int rb = n0 + row; rb = rb < N ? rb : N - 1;
      const u16* gb = Bt + (size_t)rb * K + k0 + kc * 8;
      __builtin_amdgcn_global_load_lds(
          (const __attribute__((address_space(1))) void*)gb,
          (__attribute__((address_space(3))) void*)(Bs + c * 8), 16, 0, 0);
    }
  };

  int kidx = (lk ^ ((lm >> 1) & 3)) * 8;

#pragma unroll
  for (int s = 0; s < SLOTS; ++s) {
    stage(s, s);
    asm volatile("" ::: "memory");
  }
  int buf = 0;
  for (int kt = 0; kt < NK; ++kt) {
    int rem = NK - 1 - kt;
    if (SLOTS == 3) {
      if (rem >= 2)
        asm volatile("s_waitcnt vmcnt(%0)" ::"n"(2 * LPT) : "memory");
      else if (rem == 1)
        asm volatile("s_waitcnt vmcnt(%0)" ::"n"(LPT) : "memory");
      else
        asm volatile("s_waitcnt vmcnt(0)" ::: "memory");
    } else {
      if (rem >= 1)
        asm volatile("s_waitcnt vmcnt(%0)" ::"n"(LPT) : "memory");
      else
        asm volatile("s_waitcnt vmcnt(0)" ::: "memory");
    }
    __builtin_amdgcn_s_barrier();
    asm volatile("" ::: "memory");
    const u16* As = smem + buf * BUFSZ;
    const u16* Bs = As + ABUF;
    short8 af[MI], bf[4];
#pragma unroll
    for (int i = 0; i < MI; ++i)
      af[i] = *reinterpret_cast<const short8*>(As + (wm + i * 16 + lm) * 32 + kidx);
#pragma unroll
    for (int j = 0; j < 4; ++j)
      bf[j] = *reinterpret_cast<const short8*>(Bs + (wn + j * 16 + lm) * 32 + kidx);
    __builtin_amdgcn_s_setprio(1);
#pragma unroll
    for (int i = 0; i < MI; ++i)
#pragma unroll
      for (int j = 0; j < 4; ++j)
        acc[i][j] = __builtin_amdgcn_mfma_f32_16x16x32_bf16(af[i], bf[j], acc[i][j], 0, 0, 0);
    __builtin_amdgcn_s_setprio(0);
    asm volatile("s_waitcnt lgkmcnt(0)" ::: "memory");
    __builtin_amdgcn_s_barrier();
    asm volatile("" ::: "memory");
    if (kt + SLOTS < NK) stage(buf, kt + SLOTS);
    buf = (buf == SLOTS - 1) ? 0 : buf + 1;
  }

  // epilogue. C/D frag layout: row = i*16 + lk*4 + qq, col = j*16 + lm.
  if (!OUTF32) {
    u16* ep = smem + w * (BM / 2) * 64;
#pragma unroll
    for (int j = 0; j < 4; ++j) {
      int col = n0 + wn + j * 16 + lm;
      float bv = (ACT > 0) ? bias[col < N ? col : N - 1] : 0.0f;
#pragma unroll
      for (int i = 0; i < MI; ++i)
#pragma unroll
        for (int qq = 0; qq < 4; ++qq) {
          float v = acc[i][j][qq];
          if (ACT > 0) { v += bv; v = eluf(v); }
          if (ACT == 2) v = eluf(v);
          ep[(i * 16 + lk * 4 + qq) * 64 + j * 16 + lm] = f2b(v);
        }
    }
    __syncthreads();
    u16* op = (u16*)outp;
#pragma unroll
    for (int u = 0; u < BM / 16; ++u) {
      int rrow = m0 + wm + u * 8 + (l >> 3);
      int col = n0 + wn + (l & 7) * 8;   // 8-col chunk, never crosses OSW bnd
      if (rrow < M && col < N) {
        short8 val = *reinterpret_cast<const short8*>(ep + u * 512 + l * 8);
        if (OSW) {
          int slice = col / OSW, within = col - slice * OSW;
          *reinterpret_cast<short8*>(op + (size_t)slice * NN * OSW +
                                     (size_t)rrow * OSW + within) = val;
        } else {
          *reinterpret_cast<short8*>(op + (size_t)rrow * N + col) = val;
        }
      }
    }
  } else {
    float* op = (float*)outp;
#pragma unroll
    for (int j = 0; j < 4; ++j) {
      int col = n0 + wn + j * 16 + lm;
      if (col >= N) continue;
      float bv = (ACT > 0) ? bias[col] : 0.0f;
#pragma unroll
      for (int i = 0; i < MI; ++i) {
        int rb = m0 + wm + i * 16 + lk * 4;
#pragma unroll
        for (int qq = 0; qq < 4; ++qq) {
          int rr = rb + qq;
          if (rr >= M) continue;
          float v = acc[i][j][qq];
          if (ACT > 0) { v += bv; v = eluf(v); }
          if (ACT == 2) v = eluf(v);
          op[(size_t)rr * N + col] = v;
        }
      }
    }
  }
}

// ---- DUAL GEMM: two independent K=256,N=256,BM=64,ACT=1,fp32-out GEMMs in
// one launch (x tiles [0,NT0), res tiles [NT0,2*NT0); res reads 8-sliced X).
__global__ __launch_bounds__(256) void k_gemmd(
    const u16* __restrict__ A0, const u16* __restrict__ Bt0,
    const float* __restrict__ bias0, float* __restrict__ out0,
    const u16* __restrict__ A1, const u16* __restrict__ Bt1,
    const float* __restrict__ bias1, float* __restrict__ out1) {
  constexpr int K = 256, N = 256, BM = 64;
  constexpr int NBY = 2, NK = 8, NT0 = 626;
  constexpr int ABUF = BM * 32, BUFSZ = ABUF + 4096, MI = 2, LPT = 3;
  constexpr int SLOTS = 3;
  __shared__ __align__(16) u16 smem[SLOTS * BUFSZ];
  int t = threadIdx.x;
  int l = t & 63, w = t >> 6;
  int lm = l & 15, lk = l >> 4;

  int nb = gridDim.x;
  int q8 = nb >> 3, r8 = nb & 7;
  int orig = blockIdx.x;
  int xcd = orig & 7, idx = orig >> 3;
  int wg = (xcd < r8 ? xcd * (q8 + 1) : r8 * (q8 + 1) + (xcd - r8) * q8) + idx;
  bool second = wg >= NT0;
  int tt = second ? wg - NT0 : wg;
  const u16* A = second ? A1 : A0;
  const u16* Bt = second ? Bt1 : Bt0;
  const float* bias = second ? bias1 : bias0;
  float* op = second ? out1 : out0;

  int m0 = (tt / NBY) * BM;
  int n0 = (tt % NBY) * 128;
  int wm = (w >> 1) * (BM / 2), wn = (w & 1) * 64;

  f32x4 acc[MI][4];
#pragma unroll
  for (int i = 0; i < MI; ++i)
#pragma unroll
    for (int j = 0; j < 4; ++j)
#pragma unroll
      for (int qq = 0; qq < 4; ++qq) acc[i][j][qq] = 0.0f;

  auto stage = [&](int buf, int kt) {
    int k0 = kt * 32;
    u16* As = smem + buf * BUFSZ;
    u16* Bs = As + ABUF;
    {
      int c = t;
      int row = c >> 2;
      int kc = (c & 3) ^ ((c >> 3) & 3);
      int ra = m0 + row; ra = ra < NN ? ra : NN - 1;
      const u16* ga;
      if (second)  // 8-way sliced X: [8][NN][32]; K-chunk = one slice
        ga = A + (size_t)(k0 >> 5) * NN * 32 + (size_t)ra * 32 + kc * 8;
      else
        ga = A + (size_t)ra * K + k0 + kc * 8;
      __builtin_amdgcn_global_load_lds(
          (const __attribute__((address_space(1))) void*)ga,
          (__attribute__((address_space(3))) void*)(As + c * 8), 16, 0, 0);
    }
#pragma unroll
    for (int it = 0; it < 2; ++it) {
      int c = it * 256 + t;
      int row = c >> 2;
      int kc = (c & 3) ^ ((c >> 3) & 3);
      int rb = n0 + row; rb = rb < N ? rb : N - 1;
      const u16* gb = Bt + (size_t)rb * K + k0 + kc * 8;
      __builtin_amdgcn_global_load_lds(
          (const __attribute__((address_space(1))) void*)gb,
          (__attribute__((address_space(3))) void*)(Bs + c * 8), 16, 0, 0);
    }
  };

  int kidx = (lk ^ ((lm >> 1) & 3)) * 8;

#pragma unroll
  for (int s = 0; s < SLOTS; ++s) {
    stage(s, s);
    asm volatile("" ::: "memory");
  }
  int buf = 0;
  for (int kt = 0; kt < NK; ++kt) {
    int rem = NK - 1 - kt;
    if (rem >= 2)
      asm volatile("s_waitcnt vmcnt(%0)" ::"n"(2 * LPT) : "memory");
    else if (rem == 1)
      asm volatile("s_waitcnt vmcnt(%0)" ::"n"(LPT) : "memory");
    else
      asm volatile("s_waitcnt vmcnt(0)" ::: "memory");
    __builtin_amdgcn_s_barrier();
    asm volatile("" ::: "memory");
    const u16* As = smem + buf * BUFSZ;
    const u16* Bs = As + ABUF;
    short8 af[MI], bf[4];
#pragma unroll
    for (int i = 0; i < MI; ++i)
      af[i] = *reinterpret_cast<const short8*>(As + (wm + i * 16 + lm) * 32 + kidx);
#pragma unroll
    for (int j = 0; j < 4; ++j)
      bf[j] = *reinterpret_cast<const short8*>(Bs + (wn + j * 16 + lm) * 32 + kidx);
    __builtin_amdgcn_s_setprio(1);
#pragma unroll
    for (int i = 0; i < MI; ++i)
#pragma unroll
      for (int j = 0; j < 4; ++j)
        acc[i][j] = __builtin_amdgcn_mfma_f32_16x16x32_bf16(af[i], bf[j], acc[i][j], 0, 0, 0);
    __builtin_amdgcn_s_setprio(0);
    asm volatile("s_waitcnt lgkmcnt(0)" ::: "memory");
    __builtin_amdgcn_s_barrier();
    asm volatile("" ::: "memory");
    if (kt + SLOTS < NK) stage(buf, kt + SLOTS);
    buf = (buf == SLOTS - 1) ? 0 : buf + 1;
  }

#pragma unroll
  for (int j = 0; j < 4; ++j) {
    int col = n0 + wn + j * 16 + lm;
    float bv = bias[col];
#pragma unroll
    for (int i = 0; i < MI; ++i) {
      int rb = m0 + wm + i * 16 + lk * 4;
#pragma unroll
      for (int qq = 0; qq < 4; ++qq) {
        int rr = rb + qq;
        if (rr >= NN) continue;
        float v = eluf(acc[i][j][qq] + bv);
        op[(size_t)rr * N + col] = v;
      }
    }
  }
}

extern "C" void kernel_launch(void* const* d_in, const int* in_sizes, int n_in,
                              void* d_out, int out_size, void* d_ws, size_t ws_size,
                              hipStream_t stream) {
  const float* features = (const float*)d_in[0];
  const int* eidx = (const int*)d_in[1];
  const float* w1a = (const float*)d_in[2];
  const float* b1a = (const float*)d_in[3];
  const float* w1b = (const float*)d_in[4];
  const float* b1b = (const float*)d_in[5];
  const float* w2a = (const float*)d_in[6];
  const float* b2a = (const float*)d_in[7];
  const float* w2b = (const float*)d_in[8];
  const float* b2b = (const float*)d_in[9];
  const float* w3a = (const float*)d_in[10];
  const float* b3a = (const float*)d_in[11];
  const float* w3b = (const float*)d_in[12];
  const float* b3b = (const float*)d_in[13];
  const float* wr = (const float*)d_in[14];
  const float* br = (const float*)d_in[15];

  char* ws = (char*)d_ws;
  u16* bufX = (u16*)(ws);                  // sliced x: 8*NN*32*2 = 10.24 MB
  u16* bufA = (u16*)(ws + 10240000);       // activations <= 25.6 MB
  u16* bufB = (u16*)(ws + 35840000);       // activations <= 25.6 MB
  u16* wrt = (u16*)(ws + 61440000);        // transposed bf16 weights
  u16* w1at = wrt + 256 * 256;
  u16* w1bt = w1at + 640 * 256;
  u16* w2at = w1bt + 640 * 640;
  u16* w2bt = w2at + 320 * 640;
  u16* w3at = w2bt + 320 * 320;
  u16* w3bt = w3at + 256 * 320;
  int* row_start = (int*)(ws + 63700992);  // NN+1 ints (padded to 20004)
  int* cursor = row_start + 20004;         // NN ints
  int* csr_src = cursor + NN;              // NE ints
  int* counts = csr_src + NE;              // NN ints

  const int* esrc = eidx;
  const int* edst = eidx + NE;

  // CSR build + prep: memset -> (prep: f2b-sliced + wt + hist) -> scan -> scatter
  hipMemsetAsync(counts, 0, NN * sizeof(int), stream);
  k_prep<<<10523, 256, 0, stream>>>(features, bufX, edst, counts, wr, w1a, w1b,
                                    w2a, w2b, w3a, w3b, wrt, w1at, w1bt, w2at,
                                    w2bt, w3at, w3bt);
  k_scan<<<1, 1024, 0, stream>>>(counts, row_start, cursor);
  k_scatter<<<(NE + 255) / 256, 256, 0, stream>>>(esrc, edst, cursor, csr_src, NE);

  float* out_x = (float*)d_out;
  float* out_res = (float*)d_out + (size_t)NN * 256;

  // L1: h0 = X + agg(X)   (gather 8-sliced x -> normal h0)
  k_agg<256, 0><<<8 * 313, 256, 0, stream>>>(bufX, row_start, csr_src, nullptr, bufA);
  // t1 = elu(h0 @ w1a + b1a)   [SLOTS=2: 5 blk/CU, single round]
  k_gemm<128, 256, 640, 1, false, false, 0, 2><<<dim3(157 * 5), 256, 0, stream>>>(bufA, w1at, b1a, bufB, NN);
  // x1 = elu(elu(t1 @ w1b + b1b))
  k_gemm<128, 640, 640, 2, false, false, 0, 2><<<dim3(157 * 5), 256, 0, stream>>>(bufB, w1bt, b1b, bufA, NN);
  // L2 (agg commuted past w2a): y2 = x1 @ w2a   [320-dim, 8-sliced out SW=40]
  k_gemm<128, 640, 320, 0, false, false, 40, 3><<<dim3(157 * 3), 256, 0, stream>>>(bufA, w2at, nullptr, bufB, NN);
  // t2 = elu(y2 + agg(y2) + b2a)   [NPB=51 -> 393 blocks/slice]
  k_agg<320, 1><<<8 * 393, 256, 0, stream>>>(bufB, row_start, csr_src, b2a, bufA);
  // x2 = elu(elu(t2 @ w2b + b2b))
  k_gemm<64, 320, 320, 2, false, false, 0, 3><<<dim3(313 * 3), 256, 0, stream>>>(bufA, w2bt, b2b, bufB, NN);
  // L3 (agg commuted past w3a): y3 = x2 @ w3a   [256-dim, 8-sliced out SW=32]
  k_gemm<64, 320, 256, 0, false, false, 32, 3><<<dim3(313 * 2), 256, 0, stream>>>(bufB, w3at, nullptr, bufA, NN);
  // t3 = elu(y3 + agg(y3) + b3a)
  k_agg<256, 1><<<8 * 313, 256, 0, stream>>>(bufA, row_start, csr_src, b3a, bufB);
  // x = elu(t3 @ w3b + b3b)  AND  res = elu(X @ wr + br)  (fused dual launch)
  k_gemmd<<<dim3(626 * 2), 256, 0, stream>>>(bufB, w3bt, b3b, out_x,
                                             bufX, wrt, br, out_res);
}

// Round 15
// 243.011 us; speedup vs baseline: 1.2049x; 1.0157x over previous
//
#include <hip/hip_runtime.h>
#include <cstdint>
#include <cstddef>

#define NN 20000
#define NE 320000

typedef short short8 __attribute__((ext_vector_type(8)));
typedef float f32x4 __attribute__((ext_vector_type(4)));
typedef unsigned short u16;

__device__ __forceinline__ float b2f(u16 u) {
  union { unsigned int i; float f; } z; z.i = ((unsigned int)u) << 16; return z.f;
}
__device__ __forceinline__ u16 f2b(float f) {
  union { float f; unsigned int i; } z; z.f = f;
  unsigned int r = z.i + 0x7fffu + ((z.i >> 16) & 1u);
  return (u16)(r >> 16);
}
// fast ELU: v_exp_f32-based, not libm expm1f
__device__ __forceinline__ float eluf(float v) {
  return v > 0.0f ? v : __expf(v) - 1.0f;
}

// ------- fused prep: features f2b (8-way column-SLICED out) + 7 weight
//         transposes + edge histogram. virtual tid space:
//         [0,1280000): f2b 4 elems ; [1280000,1600000): hist ; rest: weights.
__global__ __launch_bounds__(256) void k_prep(
    const float* __restrict__ features, u16* __restrict__ xbf_sliced,
    const int* __restrict__ edst, int* __restrict__ counts,
    const float* __restrict__ wr, const float* __restrict__ w1a,
    const float* __restrict__ w1b, const float* __restrict__ w2a,
    const float* __restrict__ w2b, const float* __restrict__ w3a,
    const float* __restrict__ w3b,
    u16* __restrict__ wrt, u16* __restrict__ w1at, u16* __restrict__ w1bt,
    u16* __restrict__ w2at, u16* __restrict__ w2bt, u16* __restrict__ w3at,
    u16* __restrict__ w3bt) {
  int tid = blockIdx.x * 256 + threadIdx.x;
  if (tid < 1280000) {
    int node = tid >> 6;
    int c4 = (tid & 63) * 4;           // col = c4..c4+3 (within one 32-slice)
    float4 v = *reinterpret_cast<const float4*>(features + (size_t)node * 256 + c4);
    ushort4 o;
    o.x = f2b(v.x); o.y = f2b(v.y); o.z = f2b(v.z); o.w = f2b(v.w);
    int slice = c4 >> 5, within = c4 & 31;   // 8 slices of 32 cols
    *reinterpret_cast<ushort4*>(xbf_sliced + (size_t)slice * NN * 32 +
                                (size_t)node * 32 + within) = o;
    return;
  }
  if (tid < 1600000) {
    atomicAdd(&counts[edst[tid - 1280000]], 1);
    return;
  }
  int r = tid - 1600000;
  const float* Ws[7] = {wr, w1a, w1b, w2a, w2b, w3a, w3b};
  u16* Wts[7] = {wrt, w1at, w1bt, w2at, w2bt, w3at, w3bt};
  const int Kd[7] = {256, 256, 640, 640, 320, 320, 256};
  const int Nd[7] = {256, 640, 640, 320, 320, 256, 256};
  const int cnt[7] = {65536, 163840, 409600, 204800, 102400, 81920, 65536};
#pragma unroll
  for (int j = 0; j < 7; ++j) {
    if (r < cnt[j]) {
      int n = r / Kd[j], k = r - n * Kd[j];
      Wts[j][r] = f2b(Ws[j][(size_t)k * Nd[j] + n]);
      return;
    }
    r -= cnt[j];
  }
}

// x4-vectorized single-block scan; writes exclusive prefix to BOTH rs and cur.
__global__ __launch_bounds__(1024) void k_scan(const int* __restrict__ counts,
                                               int* __restrict__ rs,
                                               int* __restrict__ cur) {
  __shared__ int wsum[16];
  __shared__ int carry_s;
  int t = threadIdx.x;
  int l = t & 63, w = t >> 6;
  if (t == 0) carry_s = 0;
  __syncthreads();
  for (int base = 0; base < NN; base += 4096) {
    int idx = base + t * 4;
    int4 v = {0, 0, 0, 0};
    if (idx < NN) v = *reinterpret_cast<const int4*>(counts + idx);
    int p0 = v.x, p1 = p0 + v.y, p2 = p1 + v.z, p3 = p2 + v.w;
    int incl = p3;
#pragma unroll
    for (int off = 1; off < 64; off <<= 1) {
      int u = __shfl_up(incl, off, 64);
      if (l >= off) incl += u;
    }
    if (l == 63) wsum[w] = incl;
    __syncthreads();  // (A) wsum ready
    int carry = carry_s;
    int wpre = 0;
    for (int k2 = 0; k2 < w; ++k2) wpre += wsum[k2];
    int tot = 0;
    if (t == 0)
      for (int k2 = 0; k2 < 16; ++k2) tot += wsum[k2];
    int ex = carry + wpre + incl - p3;
    if (idx < NN) {
      int4 o;
      o.x = ex; o.y = ex + p0; o.z = ex + p1; o.w = ex + p2;
      *reinterpret_cast<int4*>(rs + idx) = o;
      *reinterpret_cast<int4*>(cur + idx) = o;
    }
    __syncthreads();  // (B) all reads of wsum/carry_s done
    if (t == 0) carry_s = carry + tot;
    __syncthreads();  // (C) carry_s updated
  }
  if (t == 0) rs[NN] = carry_s;
}

// edge scatter (CSR) — edges-only form.
__global__ __launch_bounds__(256) void k_scatter(const int* __restrict__ src,
                                                 const int* __restrict__ dst,
                                                 int* __restrict__ cursor,
                                                 int* __restrict__ csr_src, int ne) {
  int i = blockIdx.x * 256 + threadIdx.x;
  if (i >= ne) return;
  int d = dst[i];
  int p = atomicAdd(&cursor[d], 1);
  csr_src[p] = src[i];
}

// ---- aggregation, 8-way COLUMN-SLICED gather source ------------------------
// xs layout: [8][NN][SW] bf16 (SW = D/8). Block's slice = blockIdx&7 so each
// XCD-class owns exactly ONE 1.28-1.6MB slice (L2-resident during gather).
// Output h is NORMAL [NN][D]. ACT=0: identity; ACT=1: elu(v+bias).
template <int D, int ACT>
__global__ __launch_bounds__(256) void k_agg(const u16* __restrict__ xs,
                                             const int* __restrict__ rs,
                                             const int* __restrict__ cs,
                                             const float* __restrict__ bias,
                                             u16* __restrict__ h) {
  constexpr int SW = D / 8;       // slice width (32 or 40 cols)
  constexpr int NCs = SW / 8;     // 16B chunks per slice-row (4 or 5)
  constexpr int NPB = 256 / NCs;  // nodes per block (64 or 51)
  int b = blockIdx.x;
  int slice = b & 7;
  int t = threadIdx.x;
  int nl = t / NCs, ch = t - nl * NCs;
  if (nl >= NPB) return;  // only when 256 % NCs != 0
  int node = (b >> 3) * NPB + nl;
  if (node >= NN) return;
  const u16* xp = xs + (size_t)slice * NN * SW + (size_t)ch * 8;
  float acc[8];
  {
    short8 v = *reinterpret_cast<const short8*>(xp + (size_t)node * SW);
#pragma unroll
    for (int q = 0; q < 8; ++q) acc[q] = b2f((u16)v[q]);
  }
  int e0 = rs[node], e1 = rs[node + 1];
  int e = e0;
  // 16-wide unroll: 16 independent gathers in flight (latency-bound loop)
  for (; e + 16 <= e1; e += 16) {
    int s[16];
#pragma unroll
    for (int u = 0; u < 16; ++u) s[u] = cs[e + u];
    short8 v[16];
#pragma unroll
    for (int u = 0; u < 16; ++u)
      v[u] = *reinterpret_cast<const short8*>(xp + (size_t)s[u] * SW);
#pragma unroll
    for (int q = 0; q < 8; ++q) {
      float a0 = (b2f((u16)v[0][q]) + b2f((u16)v[1][q])) +
                 (b2f((u16)v[2][q]) + b2f((u16)v[3][q]));
      float a1 = (b2f((u16)v[4][q]) + b2f((u16)v[5][q])) +
                 (b2f((u16)v[6][q]) + b2f((u16)v[7][q]));
      float a2 = (b2f((u16)v[8][q]) + b2f((u16)v[9][q])) +
                 (b2f((u16)v[10][q]) + b2f((u16)v[11][q]));
      float a3 = (b2f((u16)v[12][q]) + b2f((u16)v[13][q])) +
                 (b2f((u16)v[14][q]) + b2f((u16)v[15][q]));
      acc[q] += (a0 + a1) + (a2 + a3);
    }
  }
  for (; e + 8 <= e1; e += 8) {
    int s[8];
#pragma unroll
    for (int u = 0; u < 8; ++u) s[u] = cs[e + u];
    short8 v[8];
#pragma unroll
    for (int u = 0; u < 8; ++u)
      v[u] = *reinterpret_cast<const short8*>(xp + (size_t)s[u] * SW);
#pragma unroll
    for (int q = 0; q < 8; ++q) {
      float a0 = b2f((u16)v[0][q]) + b2f((u16)v[1][q]);
      float a1 = b2f((u16)v[2][q]) + b2f((u16)v[3][q]);
      float a2 = b2f((u16)v[4][q]) + b2f((u16)v[5][q]);
      float a3 = b2f((u16)v[6][q]) + b2f((u16)v[7][q]);
      acc[q] += (a0 + a1) + (a2 + a3);
    }
  }
  for (; e + 4 <= e1; e += 4) {
    int s0 = cs[e], s1 = cs[e + 1], s2 = cs[e + 2], s3 = cs[e + 3];
    short8 v0 = *reinterpret_cast<const short8*>(xp + (size_t)s0 * SW);
    short8 v1 = *reinterpret_cast<const short8*>(xp + (size_t)s1 * SW);
    short8 v2 = *reinterpret_cast<const short8*>(xp + (size_t)s2 * SW);
    short8 v3 = *reinterpret_cast<const short8*>(xp + (size_t)s3 * SW);
#pragma unroll
    for (int q = 0; q < 8; ++q)
      acc[q] += (b2f((u16)v0[q]) + b2f((u16)v1[q])) + (b2f((u16)v2[q]) + b2f((u16)v3[q]));
  }
  for (; e < e1; ++e) {
    int s = cs[e];
    short8 v = *reinterpret_cast<const short8*>(xp + (size_t)s * SW);
#pragma unroll
    for (int q = 0; q < 8; ++q) acc[q] += b2f((u16)v[q]);
  }
  int col0 = slice * SW + ch * 8;
  if (ACT == 1) {
    float4 b0 = *reinterpret_cast<const float4*>(bias + col0);
    float4 b1 = *reinterpret_cast<const float4*>(bias + col0 + 4);
    acc[0] = eluf(acc[0] + b0.x); acc[1] = eluf(acc[1] + b0.y);
    acc[2] = eluf(acc[2] + b0.z); acc[3] = eluf(acc[3] + b0.w);
    acc[4] = eluf(acc[4] + b1.x); acc[5] = eluf(acc[5] + b1.y);
    acc[6] = eluf(acc[6] + b1.z); acc[7] = eluf(acc[7] + b1.w);
  }
  short8 o;
#pragma unroll
  for (int q = 0; q < 8; ++q) o[q] = (short)f2b(acc[q]);
  *reinterpret_cast<short8*>(h + (size_t)node * D + col0) = o;
}

// ---------------- GEMM: C = act(A[M][K] @ B[K][N] + bias) ----------------
// A bf16 [M][K] (or 8-way column-sliced [8][M][32] when INS), Bt bf16 [N][K].
// BMx128 tile, BK=32, SLOTS-deep prefetch ring with counted vmcnt + raw
// s_barrier, issue-order fences, setprio around MFMA, 4 waves, 16x16x32 bf16
// MFMA, swizzled LDS, XCD-chunked grid.
// OSW: 0 = normal [M][N] out; else 8-way column-sliced [8][M][OSW] bf16 out.
template <int BM, int K, int N, int ACT, bool OUTF32, bool INS, int OSW, int SLOTS>
__global__ __launch_bounds__(256) void k_gemm(const u16* __restrict__ A,
                                              const u16* __restrict__ Bt,
                                              const float* __restrict__ bias,
                                              void* __restrict__ outp, int M) {
  constexpr int NBY = (N + 127) / 128;
  constexpr int NK = K / 32;
  constexpr int ABUF = BM * 32;       // u16 per A LDS buffer
  constexpr int BUFSZ = ABUF + 4096;  // A + B per ring slot
  constexpr int MI = BM / 32;         // acc i-extent per wave (2 or 4)
  constexpr int LPT = BM / 64 + 2;    // global_load_lds per thread per stage
  __shared__ __align__(16) u16 smem[SLOTS * BUFSZ];
  int t = threadIdx.x;
  int l = t & 63, w = t >> 6;
  int lm = l & 15, lk = l >> 4;

  // bijective XCD-chunked swizzle (m204)
  int nb = gridDim.x;
  int q8 = nb >> 3, r8 = nb & 7;
  int orig = blockIdx.x;
  int xcd = orig & 7, idx = orig >> 3;
  int wg = (xcd < r8 ? xcd * (q8 + 1) : r8 * (q8 + 1) + (xcd - r8) * q8) + idx;
  int m0 = (wg / NBY) * BM;
  int n0 = (wg % NBY) * 128;
  int wm = (w >> 1) * (BM / 2), wn = (w & 1) * 64;

  f32x4 acc[MI][4];
#pragma unroll
  for (int i = 0; i < MI; ++i)
#pragma unroll
    for (int j = 0; j < 4; ++j)
#pragma unroll
      for (int qq = 0; qq < 4; ++qq) acc[i][j][qq] = 0.0f;

  auto stage = [&](int buf, int kt) {
    int k0 = kt * 32;
    u16* As = smem + buf * BUFSZ;
    u16* Bs = As + ABUF;
#pragma unroll
    for (int it = 0; it < BM / 64; ++it) {  // A
      int c = it * 256 + t;
      int row = c >> 2;
      int kc = (c & 3) ^ ((c >> 3) & 3);
      int ra = m0 + row; ra = ra < M ? ra : M - 1;
      const u16* ga;
      if (INS)  // 8-way sliced A: [8][M][32]; 32-col K-chunk = one slice
        ga = A + (size_t)(k0 >> 5) * NN * 32 + (size_t)ra * 32 + kc * 8;
      else
        ga = A + (size_t)ra * K + k0 + kc * 8;
      __builtin_amdgcn_global_load_lds(
          (const __attribute__((address_space(1))) void*)ga,
          (__attribute__((address_space(3))) void*)(As + c * 8), 16, 0, 0);
    }
#pragma unroll
    for (int it = 0; it < 2; ++it) {        // B: 128*32 u16
      int c = it * 256 + t;
      int row = c >> 2;
      int kc = (c & 3) ^ ((c >> 3) & 3);
      int rb = n0 + row; rb = rb < N ? rb : N - 1;
      const u16* gb = Bt + (size_t)rb * K + k0 + kc * 8;
      __builtin_amdgcn_global_load_lds(
          (const __attribute__((address_space(1))) void*)gb,
          (__attribute__((address_space(3))) void*)(Bs + c * 8), 16, 0, 0);
    }
  };

  int kidx = (lk ^ ((lm >> 1) & 3)) * 8;

#pragma unroll
  for (int s = 0; s < SLOTS; ++s) {
    stage(s, s);
    asm volatile("" ::: "memory");
  }
  int buf = 0;
  for (int kt = 0; kt < NK; ++kt) {
    int rem = NK - 1 - kt;
    if (SLOTS == 3) {
      if (rem >= 2)
        asm volatile("s_waitcnt vmcnt(%0)" ::"n"(2 * LPT) : "memory");
      else if (rem == 1)
        asm volatile("s_waitcnt vmcnt(%0)" ::"n"(LPT) : "memory");
      else
        asm volatile("s_waitcnt vmcnt(0)" ::: "memory");
    } else {
      if (rem >= 1)
        asm volatile("s_waitcnt vmcnt(%0)" ::"n"(LPT) : "memory");
      else
        asm volatile("s_waitcnt vmcnt(0)" ::: "memory");
    }
    __builtin_amdgcn_s_barrier();
    asm volatile("" ::: "memory");
    const u16* As = smem + buf * BUFSZ;
    const u16* Bs = As + ABUF;
    short8 af[MI], bf[4];
#pragma unroll
    for (int i = 0; i < MI; ++i)
      af[i] = *reinterpret_cast<const short8*>(As + (wm + i * 16 + lm) * 32 + kidx);
#pragma unroll
    for (int j = 0; j < 4; ++j)
      bf[j] = *reinterpret_cast<const short8*>(Bs + (wn + j * 16 + lm) * 32 + kidx);
    __builtin_amdgcn_s_setprio(1);
#pragma unroll
    for (int i = 0; i < MI; ++i)
#pragma unroll
      for (int j = 0; j < 4; ++j)
        acc[i][j] = __builtin_amdgcn_mfma_f32_16x16x32_bf16(af[i], bf[j], acc[i][j], 0, 0, 0);
    __builtin_amdgcn_s_setprio(0);
    asm volatile("s_waitcnt lgkmcnt(0)" ::: "memory");
    __builtin_amdgcn_s_barrier();
    asm volatile("" ::: "memory");
    if (kt + SLOTS < NK) stage(buf, kt + SLOTS);
    buf = (buf == SLOTS - 1) ? 0 : buf + 1;
  }

  // epilogue. C/D frag layout: row = i*16 + lk*4 + qq, col = j*16 + lm.
  if (!OUTF32) {
    u16* ep = smem + w * (BM / 2) * 64;
#pragma unroll
    for (int j = 0; j < 4; ++j) {
      int col = n0 + wn + j * 16 + lm;
      float bv = (ACT > 0) ? bias[col < N ? col : N - 1] : 0.0f;
#pragma unroll
      for (int i = 0; i < MI; ++i)
#pragma unroll
        for (int qq = 0; qq < 4; ++qq) {
          float v = acc[i][j][qq];
          if (ACT > 0) { v += bv; v = eluf(v); }
          if (ACT == 2) v = eluf(v);
          ep[(i * 16 + lk * 4 + qq) * 64 + j * 16 + lm] = f2b(v);
        }
    }
    __syncthreads();
    u16* op = (u16*)outp;
#pragma unroll
    for (int u = 0; u < BM / 16; ++u) {
      int rrow = m0 + wm + u * 8 + (l >> 3);
      int col = n0 + wn + (l & 7) * 8;   // 8-col chunk, never crosses OSW bnd
      if (rrow < M && col < N) {
        short8 val = *reinterpret_cast<const short8*>(ep + u * 512 + l * 8);
        if (OSW) {
          int slice = col / OSW, within = col - slice * OSW;
          *reinterpret_cast<short8*>(op + (size_t)slice * NN * OSW +
                                     (size_t)rrow * OSW + within) = val;
        } else {
          *reinterpret_cast<short8*>(op + (size_t)rrow * N + col) = val;
        }
      }
    }
  } else {
    float* op = (float*)outp;
#pragma unroll
    for (int j = 0; j < 4; ++j) {
      int col = n0 + wn + j * 16 + lm;
      if (col >= N) continue;
      float bv = (ACT > 0) ? bias[col] : 0.0f;
#pragma unroll
      for (int i = 0; i < MI; ++i) {
        int rb = m0 + wm + i * 16 + lk * 4;
#pragma unroll
        for (int qq = 0; qq < 4; ++qq) {
          int rr = rb + qq;
          if (rr >= M) continue;
          float v = acc[i][j][qq];
          if (ACT > 0) { v += bv; v = eluf(v); }
          if (ACT == 2) v = eluf(v);
          op[(size_t)rr * N + col] = v;
        }
      }
    }
  }
}

// ---- DUAL GEMM: two independent K=256,N=256,BM=64,ACT=1,fp32-out GEMMs in
// one launch (x tiles [0,NT0), res tiles [NT0,2*NT0); res reads 8-sliced X).
// SLOTS=2: 24KB LDS -> 6 blk/CU -> capacity 1536 >= grid 1252, single round
// (R14's SLOTS=3 was a capacity-cliff mistake: 4 blk/CU -> 1024 < 1252).
__global__ __launch_bounds__(256) void k_gemmd(
    const u16* __restrict__ A0, const u16* __restrict__ Bt0,
    const float* __restrict__ bias0, float* __restrict__ out0,
    const u16* __restrict__ A1, const u16* __restrict__ Bt1,
    const float* __restrict__ bias1, float* __restrict__ out1) {
  constexpr int K = 256, N = 256, BM = 64;
  constexpr int NBY = 2, NK = 8, NT0 = 626;
  constexpr int ABUF = BM * 32, BUFSZ = ABUF + 4096, MI = 2, LPT = 3;
  constexpr int SLOTS = 2;
  __shared__ __align__(16) u16 smem[SLOTS * BUFSZ];
  int t = threadIdx.x;
  int l = t & 63, w = t >> 6;
  int lm = l & 15, lk = l >> 4;

  int nb = gridDim.x;
  int q8 = nb >> 3, r8 = nb & 7;
  int orig = blockIdx.x;
  int xcd = orig & 7, idx = orig >> 3;
  int wg = (xcd < r8 ? xcd * (q8 + 1) : r8 * (q8 + 1) + (xcd - r8) * q8) + idx;
  bool second = wg >= NT0;
  int tt = second ? wg - NT0 : wg;
  const u16* A = second ? A1 : A0;
  const u16* Bt = second ? Bt1 : Bt0;
  const float* bias = second ? bias1 : bias0;
  float* op = second ? out1 : out0;

  int m0 = (tt / NBY) * BM;
  int n0 = (tt % NBY) * 128;
  int wm = (w >> 1) * (BM / 2), wn = (w & 1) * 64;

  f32x4 acc[MI][4];
#pragma unroll
  for (int i = 0; i < MI; ++i)
#pragma unroll
    for (int j = 0; j < 4; ++j)
#pragma unroll
      for (int qq = 0; qq < 4; ++qq) acc[i][j][qq] = 0.0f;

  auto stage = [&](int buf, int kt) {
    int k0 = kt * 32;
    u16* As = smem + buf * BUFSZ;
    u16* Bs = As + ABUF;
    {
      int c = t;
      int row = c >> 2;
      int kc = (c & 3) ^ ((c >> 3) & 3);
      int ra = m0 + row; ra = ra < NN ? ra : NN - 1;
      const u16* ga;
      if (second)  // 8-way sliced X: [8][NN][32]; K-chunk = one slice
        ga = A + (size_t)(k0 >> 5) * NN * 32 + (size_t)ra * 32 + kc * 8;
      else
        ga = A + (size_t)ra * K + k0 + kc * 8;
      __builtin_amdgcn_global_load_lds(
          (const __attribute__((address_space(1))) void*)ga,
          (__attribute__((address_space(3))) void*)(As + c * 8), 16, 0, 0);
    }
#pragma unroll
    for (int it = 0; it < 2; ++it) {
      int c = it * 256 + t;
      int row = c >> 2;
      int kc = (c & 3) ^ ((c >> 3) & 3);
      int rb = n0 + row; rb = rb < N ? rb : N - 1;
      const u16* gb = Bt + (size_t)rb * K + k0 + kc * 8;
      __builtin_amdgcn_global_load_lds(
          (const __attribute__((address_space(1))) void*)gb,
          (__attribute__((address_space(3))) void*)(Bs + c * 8), 16, 0, 0);
    }
  };

  int kidx = (lk ^ ((lm >> 1) & 3)) * 8;

#pragma unroll
  for (int s = 0; s < SLOTS; ++s) {
    stage(s, s);
    asm volatile("" ::: "memory");
  }
  int buf = 0;
  for (int kt = 0; kt < NK; ++kt) {
    int rem = NK - 1 - kt;
    if (rem >= 1)
      asm volatile("s_waitcnt vmcnt(%0)" ::"n"(LPT) : "memory");
    else
      asm volatile("s_waitcnt vmcnt(0)" ::: "memory");
    __builtin_amdgcn_s_barrier();
    asm volatile("" ::: "memory");
    const u16* As = smem + buf * BUFSZ;
    const u16* Bs = As + ABUF;
    short8 af[MI], bf[4];
#pragma unroll
    for (int i = 0; i < MI; ++i)
      af[i] = *reinterpret_cast<const short8*>(As + (wm + i * 16 + lm) * 32 + kidx);
#pragma unroll
    for (int j = 0; j < 4; ++j)
      bf[j] = *reinterpret_cast<const short8*>(Bs + (wn + j * 16 + lm) * 32 + kidx);
    __builtin_amdgcn_s_setprio(1);
#pragma unroll
    for (int i = 0; i < MI; ++i)
#pragma unroll
      for (int j = 0; j < 4; ++j)
        acc[i][j] = __builtin_amdgcn_mfma_f32_16x16x32_bf16(af[i], bf[j], acc[i][j], 0, 0, 0);
    __builtin_amdgcn_s_setprio(0);
    asm volatile("s_waitcnt lgkmcnt(0)" ::: "memory");
    __builtin_amdgcn_s_barrier();
    asm volatile("" ::: "memory");
    if (kt + SLOTS < NK) stage(buf, kt + SLOTS);
    buf = (buf == SLOTS - 1) ? 0 : buf + 1;
  }

#pragma unroll
  for (int j = 0; j < 4; ++j) {
    int col = n0 + wn + j * 16 + lm;
    float bv = bias[col];
#pragma unroll
    for (int i = 0; i < MI; ++i) {
      int rb = m0 + wm + i * 16 + lk * 4;
#pragma unroll
      for (int qq = 0; qq < 4; ++qq) {
        int rr = rb + qq;
        if (rr >= NN) continue;
        float v = eluf(acc[i][j][qq] + bv);
        op[(size_t)rr * N + col] = v;
      }
    }
  }
}

extern "C" void kernel_launch(void* const* d_in, const int* in_sizes, int n_in,
                              void* d_out, int out_size, void* d_ws, size_t ws_size,
                              hipStream_t stream) {
  const float* features = (const float*)d_in[0];
  const int* eidx = (const int*)d_in[1];
  const float* w1a = (const float*)d_in[2];
  const float* b1a = (const float*)d_in[3];
  const float* w1b = (const float*)d_in[4];
  const float* b1b = (const float*)d_in[5];
  const float* w2a = (const float*)d_in[6];
  const float* b2a = (const float*)d_in[7];
  const float* w2b = (const float*)d_in[8];
  const float* b2b = (const float*)d_in[9];
  const float* w3a = (const float*)d_in[10];
  const float* b3a = (const float*)d_in[11];
  const float* w3b = (const float*)d_in[12];
  const float* b3b = (const float*)d_in[13];
  const float* wr = (const float*)d_in[14];
  const float* br = (const float*)d_in[15];

  char* ws = (char*)d_ws;
  u16* bufX = (u16*)(ws);                  // sliced x: 8*NN*32*2 = 10.24 MB
  u16* bufA = (u16*)(ws + 10240000);       // activations <= 25.6 MB
  u16* bufB = (u16*)(ws + 35840000);       // activations <= 25.6 MB
  u16* wrt = (u16*)(ws + 61440000);        // transposed bf16 weights
  u16* w1at = wrt + 256 * 256;
  u16* w1bt = w1at + 640 * 256;
  u16* w2at = w1bt + 640 * 640;
  u16* w2bt = w2at + 320 * 640;
  u16* w3at = w2bt + 320 * 320;
  u16* w3bt = w3at + 256 * 320;
  int* row_start = (int*)(ws + 63700992);  // NN+1 ints (padded to 20004)
  int* cursor = row_start + 20004;         // NN ints
  int* csr_src = cursor + NN;              // NE ints
  int* counts = csr_src + NE;              // NN ints

  const int* esrc = eidx;
  const int* edst = eidx + NE;

  // CSR build + prep: memset -> (prep: f2b-sliced + wt + hist) -> scan -> scatter
  hipMemsetAsync(counts, 0, NN * sizeof(int), stream);
  k_prep<<<10523, 256, 0, stream>>>(features, bufX, edst, counts, wr, w1a, w1b,
                                    w2a, w2b, w3a, w3b, wrt, w1at, w1bt, w2at,
                                    w2bt, w3at, w3bt);
  k_scan<<<1, 1024, 0, stream>>>(counts, row_start, cursor);
  k_scatter<<<(NE + 255) / 256, 256, 0, stream>>>(esrc, edst, cursor, csr_src, NE);

  float* out_x = (float*)d_out;
  float* out_res = (float*)d_out + (size_t)NN * 256;

  // L1: h0 = X + agg(X)   (gather 8-sliced x -> normal h0)
  k_agg<256, 0><<<8 * 313, 256, 0, stream>>>(bufX, row_start, csr_src, nullptr, bufA);
  // t1 = elu(h0 @ w1a + b1a)   [SLOTS=2: 5 blk/CU, single round at grid 785]
  k_gemm<128, 256, 640, 1, false, false, 0, 2><<<dim3(157 * 5), 256, 0, stream>>>(bufA, w1at, b1a, bufB, NN);
  // x1 = elu(elu(t1 @ w1b + b1b))
  k_gemm<128, 640, 640, 2, false, false, 0, 2><<<dim3(157 * 5), 256, 0, stream>>>(bufB, w1bt, b1b, bufA, NN);
  // L2 (agg commuted past w2a): y2 = x1 @ w2a   [320-dim, 8-sliced out SW=40;
  //   grid 471 < capacity 768 -> SLOTS=3 deeper pipeline, single round]
  k_gemm<128, 640, 320, 0, false, false, 40, 3><<<dim3(157 * 3), 256, 0, stream>>>(bufA, w2at, nullptr, bufB, NN);
  // t2 = elu(y2 + agg(y2) + b2a)   [NPB=51 -> 393 blocks/slice]
  k_agg<320, 1><<<8 * 393, 256, 0, stream>>>(bufB, row_start, csr_src, b2a, bufA);
  // x2 = elu(elu(t2 @ w2b + b2b))   [grid 939 < capacity 1024 -> SLOTS=3]
  k_gemm<64, 320, 320, 2, false, false, 0, 3><<<dim3(313 * 3), 256, 0, stream>>>(bufA, w2bt, b2b, bufB, NN);
  // L3 (agg commuted past w3a): y3 = x2 @ w3a   [256-dim, 8-sliced out SW=32;
  //   grid 626 < capacity 1024 -> SLOTS=3]
  k_gemm<64, 320, 256, 0, false, false, 32, 3><<<dim3(313 * 2), 256, 0, stream>>>(bufB, w3at, nullptr, bufA, NN);
  // t3 = elu(y3 + agg(y3) + b3a)
  k_agg<256, 1><<<8 * 313, 256, 0, stream>>>(bufA, row_start, csr_src, b3a, bufB);
  // x = elu(t3 @ w3b + b3b)  AND  res = elu(X @ wr + br)  (fused dual launch)
  k_gemmd<<<dim3(626 * 2), 256, 0, stream>>>(bufB, w3bt, b3b, out_x,
                                             bufX, wrt, br, out_res);
}

// Round 16
// 242.841 us; speedup vs baseline: 1.2057x; 1.0007x over previous
//
#include <hip/hip_runtime.h>
#include <cstdint>
#include <cstddef>

#define NN 20000
#define NE 320000

typedef short short8 __attribute__((ext_vector_type(8)));
typedef float f32x4 __attribute__((ext_vector_type(4)));
typedef unsigned short u16;

__device__ __forceinline__ float b2f(u16 u) {
  union { unsigned int i; float f; } z; z.i = ((unsigned int)u) << 16; return z.f;
}
__device__ __forceinline__ u16 f2b(float f) {
  union { float f; unsigned int i; } z; z.f = f;
  unsigned int r = z.i + 0x7fffu + ((z.i >> 16) & 1u);
  return (u16)(r >> 16);
}
// fast ELU: v_exp_f32-based, not libm expm1f
__device__ __forceinline__ float eluf(float v) {
  return v > 0.0f ? v : __expf(v) - 1.0f;
}

// ------- fused prep: features f2b (8-way column-SLICED out) + 7 weight
//         transposes + edge histogram. virtual tid space:
//         [0,1280000): f2b 4 elems ; [1280000,1600000): hist ; rest: weights.
__global__ __launch_bounds__(256) void k_prep(
    const float* __restrict__ features, u16* __restrict__ xbf_sliced,
    const int* __restrict__ edst, int* __restrict__ counts,
    const float* __restrict__ wr, const float* __restrict__ w1a,
    const float* __restrict__ w1b, const float* __restrict__ w2a,
    const float* __restrict__ w2b, const float* __restrict__ w3a,
    const float* __restrict__ w3b,
    u16* __restrict__ wrt, u16* __restrict__ w1at, u16* __restrict__ w1bt,
    u16* __restrict__ w2at, u16* __restrict__ w2bt, u16* __restrict__ w3at,
    u16* __restrict__ w3bt) {
  int tid = blockIdx.x * 256 + threadIdx.x;
  if (tid < 1280000) {
    int node = tid >> 6;
    int c4 = (tid & 63) * 4;           // col = c4..c4+3 (within one 32-slice)
    float4 v = *reinterpret_cast<const float4*>(features + (size_t)node * 256 + c4);
    ushort4 o;
    o.x = f2b(v.x); o.y = f2b(v.y); o.z = f2b(v.z); o.w = f2b(v.w);
    int slice = c4 >> 5, within = c4 & 31;   // 8 slices of 32 cols
    *reinterpret_cast<ushort4*>(xbf_sliced + (size_t)slice * NN * 32 +
                                (size_t)node * 32 + within) = o;
    return;
  }
  if (tid < 1600000) {
    atomicAdd(&counts[edst[tid - 1280000]], 1);
    return;
  }
  int r = tid - 1600000;
  const float* Ws[7] = {wr, w1a, w1b, w2a, w2b, w3a, w3b};
  u16* Wts[7] = {wrt, w1at, w1bt, w2at, w2bt, w3at, w3bt};
  const int Kd[7] = {256, 256, 640, 640, 320, 320, 256};
  const int Nd[7] = {256, 640, 640, 320, 320, 256, 256};
  const int cnt[7] = {65536, 163840, 409600, 204800, 102400, 81920, 65536};
#pragma unroll
  for (int j = 0; j < 7; ++j) {
    if (r < cnt[j]) {
      int n = r / Kd[j], k = r - n * Kd[j];
      Wts[j][r] = f2b(Ws[j][(size_t)k * Nd[j] + n]);
      return;
    }
    r -= cnt[j];
  }
}

// x4-vectorized single-block scan; writes exclusive prefix to BOTH rs and cur.
__global__ __launch_bounds__(1024) void k_scan(const int* __restrict__ counts,
                                               int* __restrict__ rs,
                                               int* __restrict__ cur) {
  __shared__ int wsum[16];
  __shared__ int carry_s;
  int t = threadIdx.x;
  int l = t & 63, w = t >> 6;
  if (t == 0) carry_s = 0;
  __syncthreads();
  for (int base = 0; base < NN; base += 4096) {
    int idx = base + t * 4;
    int4 v = {0, 0, 0, 0};
    if (idx < NN) v = *reinterpret_cast<const int4*>(counts + idx);
    int p0 = v.x, p1 = p0 + v.y, p2 = p1 + v.z, p3 = p2 + v.w;
    int incl = p3;
#pragma unroll
    for (int off = 1; off < 64; off <<= 1) {
      int u = __shfl_up(incl, off, 64);
      if (l >= off) incl += u;
    }
    if (l == 63) wsum[w] = incl;
    __syncthreads();  // (A) wsum ready
    int carry = carry_s;
    int wpre = 0;
    for (int k2 = 0; k2 < w; ++k2) wpre += wsum[k2];
    int tot = 0;
    if (t == 0)
      for (int k2 = 0; k2 < 16; ++k2) tot += wsum[k2];
    int ex = carry + wpre + incl - p3;
    if (idx < NN) {
      int4 o;
      o.x = ex; o.y = ex + p0; o.z = ex + p1; o.w = ex + p2;
      *reinterpret_cast<int4*>(rs + idx) = o;
      *reinterpret_cast<int4*>(cur + idx) = o;
    }
    __syncthreads();  // (B) all reads of wsum/carry_s done
    if (t == 0) carry_s = carry + tot;
    __syncthreads();  // (C) carry_s updated
  }
  if (t == 0) rs[NN] = carry_s;
}

// edge scatter (CSR) — edges-only form.
__global__ __launch_bounds__(256) void k_scatter(const int* __restrict__ src,
                                                 const int* __restrict__ dst,
                                                 int* __restrict__ cursor,
                                                 int* __restrict__ csr_src, int ne) {
  int i = blockIdx.x * 256 + threadIdx.x;
  if (i >= ne) return;
  int d = dst[i];
  int p = atomicAdd(&cursor[d], 1);
  csr_src[p] = src[i];
}

// ---- aggregation, 8-way COLUMN-SLICED gather source ------------------------
// xs layout: [8][NN][SW] bf16 (SW = D/8). Block's slice = blockIdx&7 so each
// XCD-class owns exactly ONE 1.28-1.6MB slice (L2-resident during gather).
// Output h is NORMAL [NN][D]. ACT=0: identity; ACT=1: elu(v+bias).
template <int D, int ACT>
__global__ __launch_bounds__(256) void k_agg(const u16* __restrict__ xs,
                                             const int* __restrict__ rs,
                                             const int* __restrict__ cs,
                                             const float* __restrict__ bias,
                                             u16* __restrict__ h) {
  constexpr int SW = D / 8;       // slice width (32 or 40 cols)
  constexpr int NCs = SW / 8;     // 16B chunks per slice-row (4 or 5)
  constexpr int NPB = 256 / NCs;  // nodes per block (64 or 51)
  int b = blockIdx.x;
  int slice = b & 7;
  int t = threadIdx.x;
  int nl = t / NCs, ch = t - nl * NCs;
  if (nl >= NPB) return;  // only when 256 % NCs != 0
  int node = (b >> 3) * NPB + nl;
  if (node >= NN) return;
  const u16* xp = xs + (size_t)slice * NN * SW + (size_t)ch * 8;
  float acc[8];
  {
    short8 v = *reinterpret_cast<const short8*>(xp + (size_t)node * SW);
#pragma unroll
    for (int q = 0; q < 8; ++q) acc[q] = b2f((u16)v[q]);
  }
  int e0 = rs[node], e1 = rs[node + 1];
  int e = e0;
  // 16-wide unroll: 16 independent gathers in flight (latency-bound loop)
  for (; e + 16 <= e1; e += 16) {
    int s[16];
#pragma unroll
    for (int u = 0; u < 16; ++u) s[u] = cs[e + u];
    short8 v[16];
#pragma unroll
    for (int u = 0; u < 16; ++u)
      v[u] = *reinterpret_cast<const short8*>(xp + (size_t)s[u] * SW);
#pragma unroll
    for (int q = 0; q < 8; ++q) {
      float a0 = (b2f((u16)v[0][q]) + b2f((u16)v[1][q])) +
                 (b2f((u16)v[2][q]) + b2f((u16)v[3][q]));
      float a1 = (b2f((u16)v[4][q]) + b2f((u16)v[5][q])) +
                 (b2f((u16)v[6][q]) + b2f((u16)v[7][q]));
      float a2 = (b2f((u16)v[8][q]) + b2f((u16)v[9][q])) +
                 (b2f((u16)v[10][q]) + b2f((u16)v[11][q]));
      float a3 = (b2f((u16)v[12][q]) + b2f((u16)v[13][q])) +
                 (b2f((u16)v[14][q]) + b2f((u16)v[15][q]));
      acc[q] += (a0 + a1) + (a2 + a3);
    }
  }
  for (; e + 8 <= e1; e += 8) {
    int s[8];
#pragma unroll
    for (int u = 0; u < 8; ++u) s[u] = cs[e + u];
    short8 v[8];
#pragma unroll
    for (int u = 0; u < 8; ++u)
      v[u] = *reinterpret_cast<const short8*>(xp + (size_t)s[u] * SW);
#pragma unroll
    for (int q = 0; q < 8; ++q) {
      float a0 = b2f((u16)v[0][q]) + b2f((u16)v[1][q]);
      float a1 = b2f((u16)v[2][q]) + b2f((u16)v[3][q]);
      float a2 = b2f((u16)v[4][q]) + b2f((u16)v[5][q]);
      float a3 = b2f((u16)v[6][q]) + b2f((u16)v[7][q]);
      acc[q] += (a0 + a1) + (a2 + a3);
    }
  }
  for (; e + 4 <= e1; e += 4) {
    int s0 = cs[e], s1 = cs[e + 1], s2 = cs[e + 2], s3 = cs[e + 3];
    short8 v0 = *reinterpret_cast<const short8*>(xp + (size_t)s0 * SW);
    short8 v1 = *reinterpret_cast<const short8*>(xp + (size_t)s1 * SW);
    short8 v2 = *reinterpret_cast<const short8*>(xp + (size_t)s2 * SW);
    short8 v3 = *reinterpret_cast<const short8*>(xp + (size_t)s3 * SW);
#pragma unroll
    for (int q = 0; q < 8; ++q)
      acc[q] += (b2f((u16)v0[q]) + b2f((u16)v1[q])) + (b2f((u16)v2[q]) + b2f((u16)v3[q]));
  }
  for (; e < e1; ++e) {
    int s = cs[e];
    short8 v = *reinterpret_cast<const short8*>(xp + (size_t)s * SW);
#pragma unroll
    for (int q = 0; q < 8; ++q) acc[q] += b2f((u16)v[q]);
  }
  int col0 = slice * SW + ch * 8;
  if (ACT == 1) {
    float4 b0 = *reinterpret_cast<const float4*>(bias + col0);
    float4 b1 = *reinterpret_cast<const float4*>(bias + col0 + 4);
    acc[0] = eluf(acc[0] + b0.x); acc[1] = eluf(acc[1] + b0.y);
    acc[2] = eluf(acc[2] + b0.z); acc[3] = eluf(acc[3] + b0.w);
    acc[4] = eluf(acc[4] + b1.x); acc[5] = eluf(acc[5] + b1.y);
    acc[6] = eluf(acc[6] + b1.z); acc[7] = eluf(acc[7] + b1.w);
  }
  short8 o;
#pragma unroll
  for (int q = 0; q < 8; ++q) o[q] = (short)f2b(acc[q]);
  *reinterpret_cast<short8*>(h + (size_t)node * D + col0) = o;
}

// ---------------- GEMM: C = act(A[M][K] @ B[K][N] + bias) ----------------
// A bf16 [M][K] (or 8-way column-sliced [8][M][32] when INS), Bt bf16 [N][K].
// BMx128 tile, BK=32, SLOTS-deep prefetch ring, counted vmcnt + raw s_barrier,
// issue-order fences, setprio around MFMA, 4 waves, 16x16x32 bf16 MFMA,
// swizzled LDS, XCD-chunked grid.
// SLOTS==3: SINGLE-barrier K-loop — stage tile kt+2 (slot (kt+2)%3 ==
//   (kt-1)%3) right after the consume barrier; safe because every wave drains
//   its slot-(kt-1) ds_reads (lgkmcnt(0)) BEFORE reaching that barrier.
// SLOTS==2: proven 2-barrier loop (2-slot ring can't defer the stage).
// OSW: 0 = normal [M][N] out; else 8-way column-sliced [8][M][OSW] bf16 out.
template <int BM, int K, int N, int ACT, bool OUTF32, bool INS, int OSW, int SLOTS>
__global__ __launch_bounds__(256) void k_gemm(const u16* __restrict__ A,
                                              const u16* __restrict__ Bt,
                                              const float* __restrict__ bias,
                                              void* __restrict__ outp, int M) {
  constexpr int NBY = (N + 127) / 128;
  constexpr int NK = K / 32;
  constexpr int ABUF = BM * 32;       // u16 per A LDS buffer
  constexpr int BUFSZ = ABUF + 4096;  // A + B per ring slot
  constexpr int MI = BM / 32;         // acc i-extent per wave (2 or 4)
  constexpr int LPT = BM / 64 + 2;    // global_load_lds per thread per stage
  __shared__ __align__(16) u16 smem[SLOTS * BUFSZ];
  int t = threadIdx.x;
  int l = t & 63, w = t >> 6;
  int lm = l & 15, lk = l >> 4;

  // bijective XCD-chunked swizzle (m204)
  int nb = gridDim.x;
  int q8 = nb >> 3, r8 = nb & 7;
  int orig = blockIdx.x;
  int xcd = orig & 7, idx = orig >> 3;
  int wg = (xcd < r8 ? xcd * (q8 + 1) : r8 * (q8 + 1) + (xcd - r8) * q8) + idx;
  int m0 = (wg / NBY) * BM;
  int n0 = (wg % NBY) * 128;
  int wm = (w >> 1) * (BM / 2), wn = (w & 1) * 64;

  f32x4 acc[MI][4];
#pragma unroll
  for (int i = 0; i < MI; ++i)
#pragma unroll
    for (int j = 0; j < 4; ++j)
#pragma unroll
      for (int qq = 0; qq < 4; ++qq) acc[i][j][qq] = 0.0f;

  auto stage = [&](int buf, int kt) {
    int k0 = kt * 32;
    u16* As = smem + buf * BUFSZ;
    u16* Bs = As + ABUF;
#pragma unroll
    for (int it = 0; it < BM / 64; ++it) {  // A
      int c = it * 256 + t;
      int row = c >> 2;
      int kc = (c & 3) ^ ((c >> 3) & 3);
      int ra = m0 + row; ra = ra < M ? ra : M - 1;
      const u16* ga;
      if (INS)  // 8-way sliced A: [8][M][32]; 32-col K-chunk = one slice
        ga = A + (size_t)(k0 >> 5) * NN * 32 + (size_t)ra * 32 + kc * 8;
      else
        ga = A + (size_t)ra * K + k0 + kc * 8;
      __builtin_amdgcn_global_load_lds(
          (const __attribute__((address_space(1))) void*)ga,
          (__attribute__((address_space(3))) void*)(As + c * 8), 16, 0, 0);
    }
#pragma unroll
    for (int it = 0; it < 2; ++it) {        // B: 128*32 u16
      int c = it * 256 + t;
      int row = c >> 2;
      int kc = (c & 3) ^ ((c >> 3) & 3);
      int rb = n0 + row; rb = rb < N ? rb : N - 1;
      const u16* gb = Bt + (size_t)rb * K + k0 + kc * 8;
      __builtin_amdgcn_global_load_lds(
          (const __attribute__((address_space(1))) void*)gb,
          (__attribute__((address_space(3))) void*)(Bs + c * 8), 16, 0, 0);
    }
  };

  int kidx = (lk ^ ((lm >> 1) & 3)) * 8;

#pragma unroll
  for (int s = 0; s < SLOTS; ++s) {
    stage(s, s);
    asm volatile("" ::: "memory");
  }
  int buf = 0;
  if (SLOTS == 3) {
    // ---- single-barrier loop ----
    for (int kt = 0; kt < NK; ++kt) {
      if (kt == 0 && NK > 2)
        asm volatile("s_waitcnt vmcnt(%0)" ::"n"(2 * LPT) : "memory");
      else if (kt < NK - 1)
        asm volatile("s_waitcnt vmcnt(%0)" ::"n"(LPT) : "memory");
      else
        asm volatile("s_waitcnt vmcnt(0)" ::: "memory");
      __builtin_amdgcn_s_barrier();        // slot kt ready; slot (kt-1) fully read
      asm volatile("" ::: "memory");
      if (kt >= 1 && kt + 2 < NK)
        stage(buf == 0 ? 2 : buf - 1, kt + 2);  // overwrite slot (kt-1)%3
      const u16* As = smem + buf * BUFSZ;
      const u16* Bs = As + ABUF;
      short8 af[MI], bf[4];
#pragma unroll
      for (int i = 0; i < MI; ++i)
        af[i] = *reinterpret_cast<const short8*>(As + (wm + i * 16 + lm) * 32 + kidx);
#pragma unroll
      for (int j = 0; j < 4; ++j)
        bf[j] = *reinterpret_cast<const short8*>(Bs + (wn + j * 16 + lm) * 32 + kidx);
      __builtin_amdgcn_s_setprio(1);
#pragma unroll
      for (int i = 0; i < MI; ++i)
#pragma unroll
        for (int j = 0; j < 4; ++j)
          acc[i][j] = __builtin_amdgcn_mfma_f32_16x16x32_bf16(af[i], bf[j], acc[i][j], 0, 0, 0);
      __builtin_amdgcn_s_setprio(0);
      // drain this wave's ds_reads of slot kt BEFORE the next consume barrier
      asm volatile("s_waitcnt lgkmcnt(0)" ::: "memory");
      buf = (buf == 2) ? 0 : buf + 1;
    }
    __syncthreads();  // all waves done reading final slot before smem reuse
  } else {
    // ---- 2-barrier loop (SLOTS==2) ----
    for (int kt = 0; kt < NK; ++kt) {
      int rem = NK - 1 - kt;
      if (rem >= 1)
        asm volatile("s_waitcnt vmcnt(%0)" ::"n"(LPT) : "memory");
      else
        asm volatile("s_waitcnt vmcnt(0)" ::: "memory");
      __builtin_amdgcn_s_barrier();
      asm volatile("" ::: "memory");
      const u16* As = smem + buf * BUFSZ;
      const u16* Bs = As + ABUF;
      short8 af[MI], bf[4];
#pragma unroll
      for (int i = 0; i < MI; ++i)
        af[i] = *reinterpret_cast<const short8*>(As + (wm + i * 16 + lm) * 32 + kidx);
#pragma unroll
      for (int j = 0; j < 4; ++j)
        bf[j] = *reinterpret_cast<const short8*>(Bs + (wn + j * 16 + lm) * 32 + kidx);
      __builtin_amdgcn_s_setprio(1);
#pragma unroll
      for (int i = 0; i < MI; ++i)
#pragma unroll
        for (int j = 0; j < 4; ++j)
          acc[i][j] = __builtin_amdgcn_mfma_f32_16x16x32_bf16(af[i], bf[j], acc[i][j], 0, 0, 0);
      __builtin_amdgcn_s_setprio(0);
      asm volatile("s_waitcnt lgkmcnt(0)" ::: "memory");
      __builtin_amdgcn_s_barrier();
      asm volatile("" ::: "memory");
      if (kt + SLOTS < NK) stage(buf, kt + SLOTS);
      buf = (buf == SLOTS - 1) ? 0 : buf + 1;
    }
  }

  // epilogue. C/D frag layout: row = i*16 + lk*4 + qq, col = j*16 + lm.
  if (!OUTF32) {
    u16* ep = smem + w * (BM / 2) * 64;
#pragma unroll
    for (int j = 0; j < 4; ++j) {
      int col = n0 + wn + j * 16 + lm;
      float bv = (ACT > 0) ? bias[col < N ? col : N - 1] : 0.0f;
#pragma unroll
      for (int i = 0; i < MI; ++i)
#pragma unroll
        for (int qq = 0; qq < 4; ++qq) {
          float v = acc[i][j][qq];
          if (ACT > 0) { v += bv; v = eluf(v); }
          if (ACT == 2) v = eluf(v);
          ep[(i * 16 + lk * 4 + qq) * 64 + j * 16 + lm] = f2b(v);
        }
    }
    __syncthreads();
    u16* op = (u16*)outp;
#pragma unroll
    for (int u = 0; u < BM / 16; ++u) {
      int rrow = m0 + wm + u * 8 + (l >> 3);
      int col = n0 + wn + (l & 7) * 8;   // 8-col chunk, never crosses OSW bnd
      if (rrow < M && col < N) {
        short8 val = *reinterpret_cast<const short8*>(ep + u * 512 + l * 8);
        if (OSW) {
          int slice = col / OSW, within = col - slice * OSW;
          *reinterpret_cast<short8*>(op + (size_t)slice * NN * OSW +
                                     (size_t)rrow * OSW + within) = val;
        } else {
          *reinterpret_cast<short8*>(op + (size_t)rrow * N + col) = val;
        }
      }
    }
  } else {
    float* op = (float*)outp;
#pragma unroll
    for (int j = 0; j < 4; ++j) {
      int col = n0 + wn + j * 16 + lm;
      if (col >= N) continue;
      float bv = (ACT > 0) ? bias[col] : 0.0f;
#pragma unroll
      for (int i = 0; i < MI; ++i) {
        int rb = m0 + wm + i * 16 + lk * 4;
#pragma unroll
        for (int qq = 0; qq < 4; ++qq) {
          int rr = rb + qq;
          if (rr >= M) continue;
          float v = acc[i][j][qq];
          if (ACT > 0) { v += bv; v = eluf(v); }
          if (ACT == 2) v = eluf(v);
          op[(size_t)rr * N + col] = v;
        }
      }
    }
  }
}

// ---- DUAL GEMM: two independent K=256,N=256,BM=64,ACT=1,fp32-out GEMMs in
// one launch (x tiles [0,NT0), res tiles [NT0,2*NT0); res reads 8-sliced X).
// SLOTS=2: 24KB LDS -> 6 blk/CU -> capacity 1536 >= grid 1252, single round.
__global__ __launch_bounds__(256) void k_gemmd(
    const u16* __restrict__ A0, const u16* __restrict__ Bt0,
    const float* __restrict__ bias0, float* __restrict__ out0,
    const u16* __restrict__ A1, const u16* __restrict__ Bt1,
    const float* __restrict__ bias1, float* __restrict__ out1) {
  constexpr int K = 256, N = 256, BM = 64;
  constexpr int NBY = 2, NK = 8, NT0 = 626;
  constexpr int ABUF = BM * 32, BUFSZ = ABUF + 4096, MI = 2, LPT = 3;
  constexpr int SLOTS = 2;
  __shared__ __align__(16) u16 smem[SLOTS * BUFSZ];
  int t = threadIdx.x;
  int l = t & 63, w = t >> 6;
  int lm = l & 15, lk = l >> 4;

  int nb = gridDim.x;
  int q8 = nb >> 3, r8 = nb & 7;
  int orig = blockIdx.x;
  int xcd = orig & 7, idx = orig >> 3;
  int wg = (xcd < r8 ? xcd * (q8 + 1) : r8 * (q8 + 1) + (xcd - r8) * q8) + idx;
  bool second = wg >= NT0;
  int tt = second ? wg - NT0 : wg;
  const u16* A = second ? A1 : A0;
  const u16* Bt = second ? Bt1 : Bt0;
  const float* bias = second ? bias1 : bias0;
  float* op = second ? out1 : out0;

  int m0 = (tt / NBY) * BM;
  int n0 = (tt % NBY) * 128;
  int wm = (w >> 1) * (BM / 2), wn = (w & 1) * 64;

  f32x4 acc[MI][4];
#pragma unroll
  for (int i = 0; i < MI; ++i)
#pragma unroll
    for (int j = 0; j < 4; ++j)
#pragma unroll
      for (int qq = 0; qq < 4; ++qq) acc[i][j][qq] = 0.0f;

  auto stage = [&](int buf, int kt) {
    int k0 = kt * 32;
    u16* As = smem + buf * BUFSZ;
    u16* Bs = As + ABUF;
    {
      int c = t;
      int row = c >> 2;
      int kc = (c & 3) ^ ((c >> 3) & 3);
      int ra = m0 + row; ra = ra < NN ? ra : NN - 1;
      const u16* ga;
      if (second)  // 8-way sliced X: [8][NN][32]; K-chunk = one slice
        ga = A + (size_t)(k0 >> 5) * NN * 32 + (size_t)ra * 32 + kc * 8;
      else
        ga = A + (size_t)ra * K + k0 + kc * 8;
      __builtin_amdgcn_global_load_lds(
          (const __attribute__((address_space(1))) void*)ga,
          (__attribute__((address_space(3))) void*)(As + c * 8), 16, 0, 0);
    }
#pragma unroll
    for (int it = 0; it < 2; ++it) {
      int c = it * 256 + t;
      int row = c >> 2;
      int kc = (c & 3) ^ ((c >> 3) & 3);
      int rb = n0 + row; rb = rb < N ? rb : N - 1;
      const u16* gb = Bt + (size_t)rb * K + k0 + kc * 8;
      __builtin_amdgcn_global_load_lds(
          (const __attribute__((address_space(1))) void*)gb,
          (__attribute__((address_space(3))) void*)(Bs + c * 8), 16, 0, 0);
    }
  };

  int kidx = (lk ^ ((lm >> 1) & 3)) * 8;

#pragma unroll
  for (int s = 0; s < SLOTS; ++s) {
    stage(s, s);
    asm volatile("" ::: "memory");
  }
  int buf = 0;
  for (int kt = 0; kt < NK; ++kt) {
    int rem = NK - 1 - kt;
    if (rem >= 1)
      asm volatile("s_waitcnt vmcnt(%0)" ::"n"(LPT) : "memory");
    else
      asm volatile("s_waitcnt vmcnt(0)" ::: "memory");
    __builtin_amdgcn_s_barrier();
    asm volatile("" ::: "memory");
    const u16* As = smem + buf * BUFSZ;
    const u16* Bs = As + ABUF;
    short8 af[MI], bf[4];
#pragma unroll
    for (int i = 0; i < MI; ++i)
      af[i] = *reinterpret_cast<const short8*>(As + (wm + i * 16 + lm) * 32 + kidx);
#pragma unroll
    for (int j = 0; j < 4; ++j)
      bf[j] = *reinterpret_cast<const short8*>(Bs + (wn + j * 16 + lm) * 32 + kidx);
    __builtin_amdgcn_s_setprio(1);
#pragma unroll
    for (int i = 0; i < MI; ++i)
#pragma unroll
      for (int j = 0; j < 4; ++j)
        acc[i][j] = __builtin_amdgcn_mfma_f32_16x16x32_bf16(af[i], bf[j], acc[i][j], 0, 0, 0);
    __builtin_amdgcn_s_setprio(0);
    asm volatile("s_waitcnt lgkmcnt(0)" ::: "memory");
    __builtin_amdgcn_s_barrier();
    asm volatile("" ::: "memory");
    if (kt + SLOTS < NK) stage(buf, kt + SLOTS);
    buf = (buf == SLOTS - 1) ? 0 : buf + 1;
  }

#pragma unroll
  for (int j = 0; j < 4; ++j) {
    int col = n0 + wn + j * 16 + lm;
    float bv = bias[col];
#pragma unroll
    for (int i = 0; i < MI; ++i) {
      int rb = m0 + wm + i * 16 + lk * 4;
#pragma unroll
      for (int qq = 0; qq < 4; ++qq) {
        int rr = rb + qq;
        if (rr >= NN) continue;
        float v = eluf(acc[i][j][qq] + bv);
        op[(size_t)rr * N + col] = v;
      }
    }
  }
}

extern "C" void kernel_launch(void* const* d_in, const int* in_sizes, int n_in,
                              void* d_out, int out_size, void* d_ws, size_t ws_size,
                              hipStream_t stream) {
  const float* features = (const float*)d_in[0];
  const int* eidx = (const int*)d_in[1];
  const float* w1a = (const float*)d_in[2];
  const float* b1a = (const float*)d_in[3];
  const float* w1b = (const float*)d_in[4];
  const float* b1b = (const float*)d_in[5];
  const float* w2a = (const float*)d_in[6];
  const float* b2a = (const float*)d_in[7];
  const float* w2b = (const float*)d_in[8];
  const float* b2b = (const float*)d_in[9];
  const float* w3a = (const float*)d_in[10];
  const float* b3a = (const float*)d_in[11];
  const float* w3b = (const float*)d_in[12];
  const float* b3b = (const float*)d_in[13];
  const float* wr = (const float*)d_in[14];
  const float* br = (const float*)d_in[15];

  char* ws = (char*)d_ws;
  u16* bufX = (u16*)(ws);                  // sliced x: 8*NN*32*2 = 10.24 MB
  u16* bufA = (u16*)(ws + 10240000);       // activations <= 25.6 MB
  u16* bufB = (u16*)(ws + 35840000);       // activations <= 25.6 MB
  u16* wrt = (u16*)(ws + 61440000);        // transposed bf16 weights
  u16* w1at = wrt + 256 * 256;
  u16* w1bt = w1at + 640 * 256;
  u16* w2at = w1bt + 640 * 640;
  u16* w2bt = w2at + 320 * 640;
  u16* w3at = w2bt + 320 * 320;
  u16* w3bt = w3at + 256 * 320;
  int* row_start = (int*)(ws + 63700992);  // NN+1 ints (padded to 20004)
  int* cursor = row_start + 20004;         // NN ints
  int* csr_src = cursor + NN;              // NE ints
  int* counts = csr_src + NE;              // NN ints

  const int* esrc = eidx;
  const int* edst = eidx + NE;

  // CSR build + prep: memset -> (prep: f2b-sliced + wt + hist) -> scan -> scatter
  hipMemsetAsync(counts, 0, NN * sizeof(int), stream);
  k_prep<<<10523, 256, 0, stream>>>(features, bufX, edst, counts, wr, w1a, w1b,
                                    w2a, w2b, w3a, w3b, wrt, w1at, w1bt, w2at,
                                    w2bt, w3at, w3bt);
  k_scan<<<1, 1024, 0, stream>>>(counts, row_start, cursor);
  k_scatter<<<(NE + 255) / 256, 256, 0, stream>>>(esrc, edst, cursor, csr_src, NE);

  float* out_x = (float*)d_out;
  float* out_res = (float*)d_out + (size_t)NN * 256;

  // L1: h0 = X + agg(X)   (gather 8-sliced x -> normal h0)
  k_agg<256, 0><<<8 * 313, 256, 0, stream>>>(bufX, row_start, csr_src, nullptr, bufA);
  // t1 = elu(h0 @ w1a + b1a)   [SLOTS=2: 5 blk/CU, single round at grid 785]
  k_gemm<128, 256, 640, 1, false, false, 0, 2><<<dim3(157 * 5), 256, 0, stream>>>(bufA, w1at, b1a, bufB, NN);
  // x1 = elu(elu(t1 @ w1b + b1b))
  k_gemm<128, 640, 640, 2, false, false, 0, 2><<<dim3(157 * 5), 256, 0, stream>>>(bufB, w1bt, b1b, bufA, NN);
  // L2 (agg commuted past w2a): y2 = x1 @ w2a   [320-dim, 8-sliced out SW=40;
  //   SLOTS=3 single-barrier, grid 471 < capacity 768]
  k_gemm<128, 640, 320, 0, false, false, 40, 3><<<dim3(157 * 3), 256, 0, stream>>>(bufA, w2at, nullptr, bufB, NN);
  // t2 = elu(y2 + agg(y2) + b2a)   [NPB=51 -> 393 blocks/slice]
  k_agg<320, 1><<<8 * 393, 256, 0, stream>>>(bufB, row_start, csr_src, b2a, bufA);
  // x2 = elu(elu(t2 @ w2b + b2b))   [SLOTS=3 single-barrier, grid 939 < 1024]
  k_gemm<64, 320, 320, 2, false, false, 0, 3><<<dim3(313 * 3), 256, 0, stream>>>(bufA, w2bt, b2b, bufB, NN);
  // L3 (agg commuted past w3a): y3 = x2 @ w3a   [256-dim, 8-sliced out SW=32;
  //   SLOTS=3 single-barrier, grid 626 < 1024]
  k_gemm<64, 320, 256, 0, false, false, 32, 3><<<dim3(313 * 2), 256, 0, stream>>>(bufB, w3at, nullptr, bufA, NN);
  // t3 = elu(y3 + agg(y3) + b3a)
  k_agg<256, 1><<<8 * 313, 256, 0, stream>>>(bufA, row_start, csr_src, b3a, bufB);
  // x = elu(t3 @ w3b + b3b)  AND  res = elu(X @ wr + br)  (fused dual launch)
  k_gemmd<<<dim3(626 * 2), 256, 0, stream>>>(bufB, w3bt, b3b, out_x,
                                             bufX, wrt, br, out_res);
}

// Round 17
// 241.576 us; speedup vs baseline: 1.2120x; 1.0052x over previous
//
#include <hip/hip_runtime.h>
#include <cstdint>
#include <cstddef>

#define NN 20000
#define NE 320000

typedef short short8 __attribute__((ext_vector_type(8)));
typedef float f32x4 __attribute__((ext_vector_type(4)));
typedef unsigned short u16;

__device__ __forceinline__ float b2f(u16 u) {
  union { unsigned int i; float f; } z; z.i = ((unsigned int)u) << 16; return z.f;
}
__device__ __forceinline__ u16 f2b(float f) {
  union { float f; unsigned int i; } z; z.f = f;
  unsigned int r = z.i + 0x7fffu + ((z.i >> 16) & 1u);
  return (u16)(r >> 16);
}
// fast ELU: v_exp_f32-based, not libm expm1f
__device__ __forceinline__ float eluf(float v) {
  return v > 0.0f ? v : __expf(v) - 1.0f;
}

// ------- fused prep: features f2b (8-way column-SLICED out) + 7 weight
//         transposes + edge histogram. virtual tid space:
//         [0,1280000): f2b 4 elems ; [1280000,1600000): hist ; rest: weights.
__global__ __launch_bounds__(256) void k_prep(
    const float* __restrict__ features, u16* __restrict__ xbf_sliced,
    const int* __restrict__ edst, int* __restrict__ counts,
    const float* __restrict__ wr, const float* __restrict__ w1a,
    const float* __restrict__ w1b, const float* __restrict__ w2a,
    const float* __restrict__ w2b, const float* __restrict__ w3a,
    const float* __restrict__ w3b,
    u16* __restrict__ wrt, u16* __restrict__ w1at, u16* __restrict__ w1bt,
    u16* __restrict__ w2at, u16* __restrict__ w2bt, u16* __restrict__ w3at,
    u16* __restrict__ w3bt) {
  int tid = blockIdx.x * 256 + threadIdx.x;
  if (tid < 1280000) {
    int node = tid >> 6;
    int c4 = (tid & 63) * 4;           // col = c4..c4+3 (within one 32-slice)
    float4 v = *reinterpret_cast<const float4*>(features + (size_t)node * 256 + c4);
    ushort4 o;
    o.x = f2b(v.x); o.y = f2b(v.y); o.z = f2b(v.z); o.w = f2b(v.w);
    int slice = c4 >> 5, within = c4 & 31;   // 8 slices of 32 cols
    *reinterpret_cast<ushort4*>(xbf_sliced + (size_t)slice * NN * 32 +
                                (size_t)node * 32 + within) = o;
    return;
  }
  if (tid < 1600000) {
    atomicAdd(&counts[edst[tid - 1280000]], 1);
    return;
  }
  int r = tid - 1600000;
  const float* Ws[7] = {wr, w1a, w1b, w2a, w2b, w3a, w3b};
  u16* Wts[7] = {wrt, w1at, w1bt, w2at, w2bt, w3at, w3bt};
  const int Kd[7] = {256, 256, 640, 640, 320, 320, 256};
  const int Nd[7] = {256, 640, 640, 320, 320, 256, 256};
  const int cnt[7] = {65536, 163840, 409600, 204800, 102400, 81920, 65536};
#pragma unroll
  for (int j = 0; j < 7; ++j) {
    if (r < cnt[j]) {
      int n = r / Kd[j], k = r - n * Kd[j];
      Wts[j][r] = f2b(Ws[j][(size_t)k * Nd[j] + n]);
      return;
    }
    r -= cnt[j];
  }
}

// x4-vectorized single-block scan; writes exclusive prefix to BOTH rs and cur.
__global__ __launch_bounds__(1024) void k_scan(const int* __restrict__ counts,
                                               int* __restrict__ rs,
                                               int* __restrict__ cur) {
  __shared__ int wsum[16];
  __shared__ int carry_s;
  int t = threadIdx.x;
  int l = t & 63, w = t >> 6;
  if (t == 0) carry_s = 0;
  __syncthreads();
  for (int base = 0; base < NN; base += 4096) {
    int idx = base + t * 4;
    int4 v = {0, 0, 0, 0};
    if (idx < NN) v = *reinterpret_cast<const int4*>(counts + idx);
    int p0 = v.x, p1 = p0 + v.y, p2 = p1 + v.z, p3 = p2 + v.w;
    int incl = p3;
#pragma unroll
    for (int off = 1; off < 64; off <<= 1) {
      int u = __shfl_up(incl, off, 64);
      if (l >= off) incl += u;
    }
    if (l == 63) wsum[w] = incl;
    __syncthreads();  // (A) wsum ready
    int carry = carry_s;
    int wpre = 0;
    for (int k2 = 0; k2 < w; ++k2) wpre += wsum[k2];
    int tot = 0;
    if (t == 0)
      for (int k2 = 0; k2 < 16; ++k2) tot += wsum[k2];
    int ex = carry + wpre + incl - p3;
    if (idx < NN) {
      int4 o;
      o.x = ex; o.y = ex + p0; o.z = ex + p1; o.w = ex + p2;
      *reinterpret_cast<int4*>(rs + idx) = o;
      *reinterpret_cast<int4*>(cur + idx) = o;
    }
    __syncthreads();  // (B) all reads of wsum/carry_s done
    if (t == 0) carry_s = carry + tot;
    __syncthreads();  // (C) carry_s updated
  }
  if (t == 0) rs[NN] = carry_s;
}

// edge scatter (CSR) — edges-only form.
__global__ __launch_bounds__(256) void k_scatter(const int* __restrict__ src,
                                                 const int* __restrict__ dst,
                                                 int* __restrict__ cursor,
                                                 int* __restrict__ csr_src, int ne) {
  int i = blockIdx.x * 256 + threadIdx.x;
  if (i >= ne) return;
  int d = dst[i];
  int p = atomicAdd(&cursor[d], 1);
  csr_src[p] = src[i];
}

// ---- aggregation, 8-way COLUMN-SLICED gather source ------------------------
// xs layout: [8][NN][SW] bf16 (SW = D/8). Block's slice = blockIdx&7 so each
// XCD-class owns exactly ONE 1.28-1.6MB slice (L2-resident during gather).
// Output h is NORMAL [NN][D]. ACT=0: identity; ACT=1: elu(v+bias).
template <int D, int ACT>
__global__ __launch_bounds__(256) void k_agg(const u16* __restrict__ xs,
                                             const int* __restrict__ rs,
                                             const int* __restrict__ cs,
                                             const float* __restrict__ bias,
                                             u16* __restrict__ h) {
  constexpr int SW = D / 8;       // slice width (32 or 40 cols)
  constexpr int NCs = SW / 8;     // 16B chunks per slice-row (4 or 5)
  constexpr int NPB = 256 / NCs;  // nodes per block (64 or 51)
  int b = blockIdx.x;
  int slice = b & 7;
  int t = threadIdx.x;
  int nl = t / NCs, ch = t - nl * NCs;
  if (nl >= NPB) return;  // only when 256 % NCs != 0
  int node = (b >> 3) * NPB + nl;
  if (node >= NN) return;
  const u16* xp = xs + (size_t)slice * NN * SW + (size_t)ch * 8;
  float acc[8];
  {
    short8 v = *reinterpret_cast<const short8*>(xp + (size_t)node * SW);
#pragma unroll
    for (int q = 0; q < 8; ++q) acc[q] = b2f((u16)v[q]);
  }
  int e0 = rs[node], e1 = rs[node + 1];
  int e = e0;
  // 16-wide unroll: 16 independent gathers in flight (latency-bound loop)
  for (; e + 16 <= e1; e += 16) {
    int s[16];
#pragma unroll
    for (int u = 0; u < 16; ++u) s[u] = cs[e + u];
    short8 v[16];
#pragma unroll
    for (int u = 0; u < 16; ++u)
      v[u] = *reinterpret_cast<const short8*>(xp + (size_t)s[u] * SW);
#pragma unroll
    for (int q = 0; q < 8; ++q) {
      float a0 = (b2f((u16)v[0][q]) + b2f((u16)v[1][q])) +
                 (b2f((u16)v[2][q]) + b2f((u16)v[3][q]));
      float a1 = (b2f((u16)v[4][q]) + b2f((u16)v[5][q])) +
                 (b2f((u16)v[6][q]) + b2f((u16)v[7][q]));
      float a2 = (b2f((u16)v[8][q]) + b2f((u16)v[9][q])) +
                 (b2f((u16)v[10][q]) + b2f((u16)v[11][q]));
      float a3 = (b2f((u16)v[12][q]) + b2f((u16)v[13][q])) +
                 (b2f((u16)v[14][q]) + b2f((u16)v[15][q]));
      acc[q] += (a0 + a1) + (a2 + a3);
    }
  }
  for (; e + 8 <= e1; e += 8) {
    int s[8];
#pragma unroll
    for (int u = 0; u < 8; ++u) s[u] = cs[e + u];
    short8 v[8];
#pragma unroll
    for (int u = 0; u < 8; ++u)
      v[u] = *reinterpret_cast<const short8*>(xp + (size_t)s[u] * SW);
#pragma unroll
    for (int q = 0; q < 8; ++q) {
      float a0 = b2f((u16)v[0][q]) + b2f((u16)v[1][q]);
      float a1 = b2f((u16)v[2][q]) + b2f((u16)v[3][q]);
      float a2 = b2f((u16)v[4][q]) + b2f((u16)v[5][q]);
      float a3 = b2f((u16)v[6][q]) + b2f((u16)v[7][q]);
      acc[q] += (a0 + a1) + (a2 + a3);
    }
  }
  for (; e + 4 <= e1; e += 4) {
    int s0 = cs[e], s1 = cs[e + 1], s2 = cs[e + 2], s3 = cs[e + 3];
    short8 v0 = *reinterpret_cast<const short8*>(xp + (size_t)s0 * SW);
    short8 v1 = *reinterpret_cast<const short8*>(xp + (size_t)s1 * SW);
    short8 v2 = *reinterpret_cast<const short8*>(xp + (size_t)s2 * SW);
    short8 v3 = *reinterpret_cast<const short8*>(xp + (size_t)s3 * SW);
#pragma unroll
    for (int q = 0; q < 8; ++q)
      acc[q] += (b2f((u16)v0[q]) + b2f((u16)v1[q])) + (b2f((u16)v2[q]) + b2f((u16)v3[q]));
  }
  for (; e < e1; ++e) {
    int s = cs[e];
    short8 v = *reinterpret_cast<const short8*>(xp + (size_t)s * SW);
#pragma unroll
    for (int q = 0; q < 8; ++q) acc[q] += b2f((u16)v[q]);
  }
  int col0 = slice * SW + ch * 8;
  if (ACT == 1) {
    float4 b0 = *reinterpret_cast<const float4*>(bias + col0);
    float4 b1 = *reinterpret_cast<const float4*>(bias + col0 + 4);
    acc[0] = eluf(acc[0] + b0.x); acc[1] = eluf(acc[1] + b0.y);
    acc[2] = eluf(acc[2] + b0.z); acc[3] = eluf(acc[3] + b0.w);
    acc[4] = eluf(acc[4] + b1.x); acc[5] = eluf(acc[5] + b1.y);
    acc[6] = eluf(acc[6] + b1.z); acc[7] = eluf(acc[7] + b1.w);
  }
  short8 o;
#pragma unroll
  for (int q = 0; q < 8; ++q) o[q] = (short)f2b(acc[q]);
  *reinterpret_cast<short8*>(h + (size_t)node * D + col0) = o;
}

// ---------------- GEMM: C = act(A[M][K] @ B[K][N] + bias) ----------------
// A bf16 [M][K] (or 8-way column-sliced [8][M][32] when INS), Bt bf16 [N][K].
// BMx128 tile, BK=32, SLOTS-deep prefetch ring, counted vmcnt + raw s_barrier,
// issue-order fences, setprio around MFMA, 4 waves, 16x16x32 bf16 MFMA,
// swizzled LDS, XCD-chunked grid.
// SLOTS==3: single-barrier K-loop (R16-proven).  SLOTS==2: 2-barrier loop.
// OSW: 0 = normal [M][N] out; else 8-way column-sliced [8][M][OSW] bf16 out.
template <int BM, int K, int N, int ACT, bool OUTF32, bool INS, int OSW, int SLOTS>
__global__ __launch_bounds__(256) void k_gemm(const u16* __restrict__ A,
                                              const u16* __restrict__ Bt,
                                              const float* __restrict__ bias,
                                              void* __restrict__ outp, int M) {
  constexpr int NBY = (N + 127) / 128;
  constexpr int NK = K / 32;
  constexpr int ABUF = BM * 32;       // u16 per A LDS buffer
  constexpr int BUFSZ = ABUF + 4096;  // A + B per ring slot
  constexpr int MI = BM / 32;         // acc i-extent per wave (2 or 4)
  constexpr int LPT = BM / 64 + 2;    // global_load_lds per thread per stage
  __shared__ __align__(16) u16 smem[SLOTS * BUFSZ];
  int t = threadIdx.x;
  int l = t & 63, w = t >> 6;
  int lm = l & 15, lk = l >> 4;

  // bijective XCD-chunked swizzle (m204)
  int nb = gridDim.x;
  int q8 = nb >> 3, r8 = nb & 7;
  int orig = blockIdx.x;
  int xcd = orig & 7, idx = orig >> 3;
  int wg = (xcd < r8 ? xcd * (q8 + 1) : r8 * (q8 + 1) + (xcd - r8) * q8) + idx;
  int m0 = (wg / NBY) * BM;
  int n0 = (wg % NBY) * 128;
  int wm = (w >> 1) * (BM / 2), wn = (w & 1) * 64;

  f32x4 acc[MI][4];
#pragma unroll
  for (int i = 0; i < MI; ++i)
#pragma unroll
    for (int j = 0; j < 4; ++j)
#pragma unroll
      for (int qq = 0; qq < 4; ++qq) acc[i][j][qq] = 0.0f;

  auto stage = [&](int buf, int kt) {
    int k0 = kt * 32;
    u16* As = smem + buf * BUFSZ;
    u16* Bs = As + ABUF;
#pragma unroll
    for (int it = 0; it < BM / 64; ++it) {  // A
      int c = it * 256 + t;
      int row = c >> 2;
      int kc = (c & 3) ^ ((c >> 3) & 3);
      int ra = m0 + row; ra = ra < M ? ra : M - 1;
      const u16* ga;
      if (INS)  // 8-way sliced A: [8][M][32]; 32-col K-chunk = one slice
        ga = A + (size_t)(k0 >> 5) * NN * 32 + (size_t)ra * 32 + kc * 8;
      else
        ga = A + (size_t)ra * K + k0 + kc * 8;
      __builtin_amdgcn_global_load_lds(
          (const __attribute__((address_space(1))) void*)ga,
          (__attribute__((address_space(3))) void*)(As + c * 8), 16, 0, 0);
    }
#pragma unroll
    for (int it = 0; it < 2; ++it) {        // B: 128*32 u16
      int c = it * 256 + t;
      int row = c >> 2;
      int kc = (c & 3) ^ ((c >> 3) & 3);
      int rb = n0 + row; rb = rb < N ? rb : N - 1;
      const u16* gb = Bt + (size_t)rb * K + k0 + kc * 8;
      __builtin_amdgcn_global_load_lds(
          (const __attribute__((address_space(1))) void*)gb,
          (__attribute__((address_space(3))) void*)(Bs + c * 8), 16, 0, 0);
    }
  };

  int kidx = (lk ^ ((lm >> 1) & 3)) * 8;

#pragma unroll
  for (int s = 0; s < SLOTS; ++s) {
    stage(s, s);
    asm volatile("" ::: "memory");
  }
  int buf = 0;
  if (SLOTS == 3) {
    // ---- single-barrier loop (R16-proven) ----
    for (int kt = 0; kt < NK; ++kt) {
      if (kt == 0 && NK > 2)
        asm volatile("s_waitcnt vmcnt(%0)" ::"n"(2 * LPT) : "memory");
      else if (kt < NK - 1)
        asm volatile("s_waitcnt vmcnt(%0)" ::"n"(LPT) : "memory");
      else
        asm volatile("s_waitcnt vmcnt(0)" ::: "memory");
      __builtin_amdgcn_s_barrier();        // slot kt ready; slot (kt-1) fully read
      asm volatile("" ::: "memory");
      if (kt >= 1 && kt + 2 < NK)
        stage(buf == 0 ? 2 : buf - 1, kt + 2);  // overwrite slot (kt-1)%3
      const u16* As = smem + buf * BUFSZ;
      const u16* Bs = As + ABUF;
      short8 af[MI], bf[4];
#pragma unroll
      for (int i = 0; i < MI; ++i)
        af[i] = *reinterpret_cast<const short8*>(As + (wm + i * 16 + lm) * 32 + kidx);
#pragma unroll
      for (int j = 0; j < 4; ++j)
        bf[j] = *reinterpret_cast<const short8*>(Bs + (wn + j * 16 + lm) * 32 + kidx);
      __builtin_amdgcn_s_setprio(1);
#pragma unroll
      for (int i = 0; i < MI; ++i)
#pragma unroll
        for (int j = 0; j < 4; ++j)
          acc[i][j] = __builtin_amdgcn_mfma_f32_16x16x32_bf16(af[i], bf[j], acc[i][j], 0, 0, 0);
      __builtin_amdgcn_s_setprio(0);
      // drain this wave's ds_reads of slot kt BEFORE the next consume barrier
      asm volatile("s_waitcnt lgkmcnt(0)" ::: "memory");
      buf = (buf == 2) ? 0 : buf + 1;
    }
    __syncthreads();  // all waves done reading final slot before smem reuse
  } else {
    // ---- 2-barrier loop (SLOTS==2) ----
    for (int kt = 0; kt < NK; ++kt) {
      int rem = NK - 1 - kt;
      if (rem >= 1)
        asm volatile("s_waitcnt vmcnt(%0)" ::"n"(LPT) : "memory");
      else
        asm volatile("s_waitcnt vmcnt(0)" ::: "memory");
      __builtin_amdgcn_s_barrier();
      asm volatile("" ::: "memory");
      const u16* As = smem + buf * BUFSZ;
      const u16* Bs = As + ABUF;
      short8 af[MI], bf[4];
#pragma unroll
      for (int i = 0; i < MI; ++i)
        af[i] = *reinterpret_cast<const short8*>(As + (wm + i * 16 + lm) * 32 + kidx);
#pragma unroll
      for (int j = 0; j < 4; ++j)
        bf[j] = *reinterpret_cast<const short8*>(Bs + (wn + j * 16 + lm) * 32 + kidx);
      __builtin_amdgcn_s_setprio(1);
#pragma unroll
      for (int i = 0; i < MI; ++i)
#pragma unroll
        for (int j = 0; j < 4; ++j)
          acc[i][j] = __builtin_amdgcn_mfma_f32_16x16x32_bf16(af[i], bf[j], acc[i][j], 0, 0, 0);
      __builtin_amdgcn_s_setprio(0);
      asm volatile("s_waitcnt lgkmcnt(0)" ::: "memory");
      __builtin_amdgcn_s_barrier();
      asm volatile("" ::: "memory");
      if (kt + SLOTS < NK) stage(buf, kt + SLOTS);
      buf = (buf == SLOTS - 1) ? 0 : buf + 1;
    }
  }

  // epilogue. C/D frag layout: row = i*16 + lk*4 + qq, col = j*16 + lm.
  if (!OUTF32) {
    u16* ep = smem + w * (BM / 2) * 64;
#pragma unroll
    for (int j = 0; j < 4; ++j) {
      int col = n0 + wn + j * 16 + lm;
      float bv = (ACT > 0) ? bias[col < N ? col : N - 1] : 0.0f;
#pragma unroll
      for (int i = 0; i < MI; ++i)
#pragma unroll
        for (int qq = 0; qq < 4; ++qq) {
          float v = acc[i][j][qq];
          if (ACT > 0) { v += bv; v = eluf(v); }
          if (ACT == 2) v = eluf(v);
          ep[(i * 16 + lk * 4 + qq) * 64 + j * 16 + lm] = f2b(v);
        }
    }
    __syncthreads();
    u16* op = (u16*)outp;
#pragma unroll
    for (int u = 0; u < BM / 16; ++u) {
      int rrow = m0 + wm + u * 8 + (l >> 3);
      int col = n0 + wn + (l & 7) * 8;   // 8-col chunk, never crosses OSW bnd
      if (rrow < M && col < N) {
        short8 val = *reinterpret_cast<const short8*>(ep + u * 512 + l * 8);
        if (OSW) {
          int slice = col / OSW, within = col - slice * OSW;
          *reinterpret_cast<short8*>(op + (size_t)slice * NN * OSW +
                                     (size_t)rrow * OSW + within) = val;
        } else {
          *reinterpret_cast<short8*>(op + (size_t)rrow * N + col) = val;
        }
      }
    }
  } else {
    float* op = (float*)outp;
#pragma unroll
    for (int j = 0; j < 4; ++j) {
      int col = n0 + wn + j * 16 + lm;
      if (col >= N) continue;
      float bv = (ACT > 0) ? bias[col] : 0.0f;
#pragma unroll
      for (int i = 0; i < MI; ++i) {
        int rb = m0 + wm + i * 16 + lk * 4;
#pragma unroll
        for (int qq = 0; qq < 4; ++qq) {
          int rr = rb + qq;
          if (rr >= M) continue;
          float v = acc[i][j][qq];
          if (ACT > 0) { v += bv; v = eluf(v); }
          if (ACT == 2) v = eluf(v);
          op[(size_t)rr * N + col] = v;
        }
      }
    }
  }
}

// ---- DUAL GEMM: two independent K=256,N=256,BM=64,ACT=1,fp32-out GEMMs in
// one launch (x tiles [0,NT0), res tiles [NT0,2*NT0); res reads 8-sliced X).
// SLOTS=2: 24KB LDS -> 6 blk/CU -> capacity 1536 >= grid 1252, single round.
__global__ __launch_bounds__(256) void k_gemmd(
    const u16* __restrict__ A0, const u16* __restrict__ Bt0,
    const float* __restrict__ bias0, float* __restrict__ out0,
    const u16* __restrict__ A1, const u16* __restrict__ Bt1,
    const float* __restrict__ bias1, float* __restrict__ out1) {
  constexpr int K = 256, N = 256, BM = 64;
  constexpr int NBY = 2, NK = 8, NT0 = 626;
  constexpr int ABUF = BM * 32, BUFSZ = ABUF + 4096, MI = 2, LPT = 3;
  constexpr int SLOTS = 2;
  __shared__ __align__(16) u16 smem[SLOTS * BUFSZ];
  int t = threadIdx.x;
  int l = t & 63, w = t >> 6;
  int lm = l & 15, lk = l >> 4;

  int nb = gridDim.x;
  int q8 = nb >> 3, r8 = nb & 7;
  int orig = blockIdx.x;
  int xcd = orig & 7, idx = orig >> 3;
  int wg = (xcd < r8 ? xcd * (q8 + 1) : r8 * (q8 + 1) + (xcd - r8) * q8) + idx;
  bool second = wg >= NT0;
  int tt = second ? wg - NT0 : wg;
  const u16* A = second ? A1 : A0;
  const u16* Bt = second ? Bt1 : Bt0;
  const float* bias = second ? bias1 : bias0;
  float* op = second ? out1 : out0;

  int m0 = (tt / NBY) * BM;
  int n0 = (tt % NBY) * 128;
  int wm = (w >> 1) * (BM / 2), wn = (w & 1) * 64;

  f32x4 acc[MI][4];
#pragma unroll
  for (int i = 0; i < MI; ++i)
#pragma unroll
    for (int j = 0; j < 4; ++j)
#pragma unroll
      for (int qq = 0; qq < 4; ++qq) acc[i][j][qq] = 0.0f;

  auto stage = [&](int buf, int kt) {
    int k0 = kt * 32;
    u16* As = smem + buf * BUFSZ;
    u16* Bs = As + ABUF;
    {
      int c = t;
      int row = c >> 2;
      int kc = (c & 3) ^ ((c >> 3) & 3);
      int ra = m0 + row; ra = ra < NN ? ra : NN - 1;
      const u16* ga;
      if (second)  // 8-way sliced X: [8][NN][32]; K-chunk = one slice
        ga = A + (size_t)(k0 >> 5) * NN * 32 + (size_t)ra * 32 + kc * 8;
      else
        ga = A + (size_t)ra * K + k0 + kc * 8;
      __builtin_amdgcn_global_load_lds(
          (const __attribute__((address_space(1))) void*)ga,
          (__attribute__((address_space(3))) void*)(As + c * 8), 16, 0, 0);
    }
#pragma unroll
    for (int it = 0; it < 2; ++it) {
      int c = it * 256 + t;
      int row = c >> 2;
      int kc = (c & 3) ^ ((c >> 3) & 3);
      int rb = n0 + row; rb = rb < N ? rb : N - 1;
      const u16* gb = Bt + (size_t)rb * K + k0 + kc * 8;
      __builtin_amdgcn_global_load_lds(
          (const __attribute__((address_space(1))) void*)gb,
          (__attribute__((address_space(3))) void*)(Bs + c * 8), 16, 0, 0);
    }
  };

  int kidx = (lk ^ ((lm >> 1) & 3)) * 8;

#pragma unroll
  for (int s = 0; s < SLOTS; ++s) {
    stage(s, s);
    asm volatile("" ::: "memory");
  }
  int buf = 0;
  for (int kt = 0; kt < NK; ++kt) {
    int rem = NK - 1 - kt;
    if (rem >= 1)
      asm volatile("s_waitcnt vmcnt(%0)" ::"n"(LPT) : "memory");
    else
      asm volatile("s_waitcnt vmcnt(0)" ::: "memory");
    __builtin_amdgcn_s_barrier();
    asm volatile("" ::: "memory");
    const u16* As = smem + buf * BUFSZ;
    const u16* Bs = As + ABUF;
    short8 af[MI], bf[4];
#pragma unroll
    for (int i = 0; i < MI; ++i)
      af[i] = *reinterpret_cast<const short8*>(As + (wm + i * 16 + lm) * 32 + kidx);
#pragma unroll
    for (int j = 0; j < 4; ++j)
      bf[j] = *reinterpret_cast<const short8*>(Bs + (wn + j * 16 + lm) * 32 + kidx);
    __builtin_amdgcn_s_setprio(1);
#pragma unroll
    for (int i = 0; i < MI; ++i)
#pragma unroll
      for (int j = 0; j < 4; ++j)
        acc[i][j] = __builtin_amdgcn_mfma_f32_16x16x32_bf16(af[i], bf[j], acc[i][j], 0, 0, 0);
    __builtin_amdgcn_s_setprio(0);
    asm volatile("s_waitcnt lgkmcnt(0)" ::: "memory");
    __builtin_amdgcn_s_barrier();
    asm volatile("" ::: "memory");
    if (kt + SLOTS < NK) stage(buf, kt + SLOTS);
    buf = (buf == SLOTS - 1) ? 0 : buf + 1;
  }

#pragma unroll
  for (int j = 0; j < 4; ++j) {
    int col = n0 + wn + j * 16 + lm;
    float bv = bias[col];
#pragma unroll
    for (int i = 0; i < MI; ++i) {
      int rb = m0 + wm + i * 16 + lk * 4;
#pragma unroll
      for (int qq = 0; qq < 4; ++qq) {
        int rr = rb + qq;
        if (rr >= NN) continue;
        float v = eluf(acc[i][j][qq] + bv);
        op[(size_t)rr * N + col] = v;
      }
    }
  }
}

extern "C" void kernel_launch(void* const* d_in, const int* in_sizes, int n_in,
                              void* d_out, int out_size, void* d_ws, size_t ws_size,
                              hipStream_t stream) {
  const float* features = (const float*)d_in[0];
  const int* eidx = (const int*)d_in[1];
  const float* w1a = (const float*)d_in[2];
  const float* b1a = (const float*)d_in[3];
  const float* w1b = (const float*)d_in[4];
  const float* b1b = (const float*)d_in[5];
  const float* w2a = (const float*)d_in[6];
  const float* b2a = (const float*)d_in[7];
  const float* w2b = (const float*)d_in[8];
  const float* b2b = (const float*)d_in[9];
  const float* w3a = (const float*)d_in[10];
  const float* b3a = (const float*)d_in[11];
  const float* w3b = (const float*)d_in[12];
  const float* b3b = (const float*)d_in[13];
  const float* wr = (const float*)d_in[14];
  const float* br = (const float*)d_in[15];

  char* ws = (char*)d_ws;
  u16* bufX = (u16*)(ws);                  // sliced x: 8*NN*32*2 = 10.24 MB
  u16* bufA = (u16*)(ws + 10240000);       // activations <= 25.6 MB
  u16* bufB = (u16*)(ws + 35840000);       // activations <= 25.6 MB
  u16* wrt = (u16*)(ws + 61440000);        // transposed bf16 weights
  u16* w1at = wrt + 256 * 256;
  u16* w1bt = w1at + 640 * 256;
  u16* w2at = w1bt + 640 * 640;
  u16* w2bt = w2at + 320 * 640;
  u16* w3at = w2bt + 320 * 320;
  u16* w3bt = w3at + 256 * 320;
  int* row_start = (int*)(ws + 63700992);  // NN+1 ints (padded to 20004)
  int* cursor = row_start + 20004;         // NN ints
  int* csr_src = cursor + NN;              // NE ints
  int* counts = csr_src + NE;              // NN ints

  const int* esrc = eidx;
  const int* edst = eidx + NE;

  // CSR build + prep: memset -> (prep: f2b-sliced + wt + hist) -> scan -> scatter
  hipMemsetAsync(counts, 0, NN * sizeof(int), stream);
  k_prep<<<10523, 256, 0, stream>>>(features, bufX, edst, counts, wr, w1a, w1b,
                                    w2a, w2b, w3a, w3b, wrt, w1at, w1bt, w2at,
                                    w2bt, w3at, w3bt);
  k_scan<<<1, 1024, 0, stream>>>(counts, row_start, cursor);
  k_scatter<<<(NE + 255) / 256, 256, 0, stream>>>(esrc, edst, cursor, csr_src, NE);

  float* out_x = (float*)d_out;
  float* out_res = (float*)d_out + (size_t)NN * 256;

  // L1: h0 = X + agg(X)   (gather 8-sliced x -> normal h0)
  k_agg<256, 0><<<8 * 313, 256, 0, stream>>>(bufX, row_start, csr_src, nullptr, bufA);
  // t1 = elu(h0 @ w1a + b1a)   [A/B: SLOTS=3 deeper cover, accepts 17-tile
  //   straggler round (785 > 768 capacity at 3 blk/CU)]
  k_gemm<128, 256, 640, 1, false, false, 0, 3><<<dim3(157 * 5), 256, 0, stream>>>(bufA, w1at, b1a, bufB, NN);
  // x1 = elu(elu(t1 @ w1b + b1b))   [A/B: SLOTS=3]
  k_gemm<128, 640, 640, 2, false, false, 0, 3><<<dim3(157 * 5), 256, 0, stream>>>(bufB, w1bt, b1b, bufA, NN);
  // L2 (agg commuted past w2a): y2 = x1 @ w2a   [320-dim, 8-sliced out SW=40;
  //   SLOTS=3 single-barrier, grid 471 < capacity 768]
  k_gemm<128, 640, 320, 0, false, false, 40, 3><<<dim3(157 * 3), 256, 0, stream>>>(bufA, w2at, nullptr, bufB, NN);
  // t2 = elu(y2 + agg(y2) + b2a)   [NPB=51 -> 393 blocks/slice]
  k_agg<320, 1><<<8 * 393, 256, 0, stream>>>(bufB, row_start, csr_src, b2a, bufA);
  // x2 = elu(elu(t2 @ w2b + b2b))   [SLOTS=3 single-barrier, grid 939 < 1024]
  k_gemm<64, 320, 320, 2, false, false, 0, 3><<<dim3(313 * 3), 256, 0, stream>>>(bufA, w2bt, b2b, bufB, NN);
  // L3 (agg commuted past w3a): y3 = x2 @ w3a   [256-dim, 8-sliced out SW=32;
  //   SLOTS=3 single-barrier, grid 626 < 1024]
  k_gemm<64, 320, 256, 0, false, false, 32, 3><<<dim3(313 * 2), 256, 0, stream>>>(bufB, w3at, nullptr, bufA, NN);
  // t3 = elu(y3 + agg(y3) + b3a)
  k_agg<256, 1><<<8 * 313, 256, 0, stream>>>(bufA, row_start, csr_src, b3a, bufB);
  // x = elu(t3 @ w3b + b3b)  AND  res = elu(X @ wr + br)  (fused dual launch)
  k_gemmd<<<dim3(626 * 2), 256, 0, stream>>>(bufB, w3bt, b3b, out_x,
                                             bufX, wrt, br, out_res);
}